// Round 1
// baseline (7687.049 us; speedup 1.0000x reference)
//
#include <hip/hip_runtime.h>
#include <hip/hip_bf16.h>
#include <math.h>

// ---------------- problem dims (fixed by setup_inputs) ----------------
#define BTOT 1536            // B*T = 32*48
// linguistic
#define EL 300
#define WL_ 33
#define KL 5
#define CL 128
#define LOUTL 29
#define KDIML 1500
#define KPADL 1504
// acoustic
#define EA 988
#define WA_ 50
#define KA 10
#define CA 256
#define LOUTA 41
#define KDIMA 9880
#define KPADA 9888
// emotient
#define EE 20
#define WE_ 30
#define HH 128
#define KE 3
#define CE 64
#define LOUTE 28
#define KDIME 384
#define KPADE 384

// ---------------- weight prep: conv w (Cout,Cin,K) -> wt[p][Cout], p=k*Cin+c, zero-pad to KPAD ----------------
template<int CIN, int KW, int COUT, int KPAD>
__global__ void prep_wt(const float* __restrict__ w, float* __restrict__ wt) {
    int idx = blockIdx.x * blockDim.x + threadIdx.x;
    if (idx >= KPAD * COUT) return;
    int p  = idx / COUT;
    int co = idx - p * COUT;
    float v = 0.f;
    if (p < CIN * KW) {
        int c = p % CIN;
        int k = p / CIN;
        v = w[(co * CIN + c) * KW + k];
    }
    wt[idx] = v;
}

// generic transpose: a (R,C) -> at (C,R)
__global__ void transpose_mat(const float* __restrict__ a, float* __restrict__ at, int R, int C) {
    int idx = blockIdx.x * blockDim.x + threadIdx.x;
    if (idx >= R * C) return;
    int r = idx / C, c = idx - r * C;
    at[c * R + r] = a[idx];
}

// ---------------- fused conv1d + maxpool-over-length ----------------
// x: (BTOT, WIN, CIN) row-major; A[(bt,l)][p] = x[bt, l*CIN + p] (contiguous window).
// wt: (KPAD, COUT) zero-padded. pooled[bt][co] = max_l conv + bias.
template<int CIN, int WIN, int COUT, int KDIM, int KPAD, int LOUT, int MT>
__global__ __launch_bounds__(256)
void conv_max_kernel(const float* __restrict__ x, const float* __restrict__ wt,
                     const float* __restrict__ bias, float* __restrict__ pooled) {
    constexpr int BK = 32;
    constexpr int NT = 64;
    constexpr int RPT = MT / 16;
    int bt  = blockIdx.x;
    int co0 = blockIdx.y * NT;
    __shared__ float As[MT][BK + 1];
    __shared__ __align__(16) float Bs[BK][NT];
    __shared__ float pmax[16][NT];
    int tid = threadIdx.x;
    int tc = tid & 15;
    int tr = tid >> 4;

    float acc[RPT][4];
    #pragma unroll
    for (int i = 0; i < RPT; ++i)
        #pragma unroll
        for (int j = 0; j < 4; ++j) acc[i][j] = 0.f;

    const float* xb = x + (size_t)bt * WIN * CIN;

    for (int k0 = 0; k0 < KPAD; k0 += BK) {
        // stage A tile (MT x BK)
        #pragma unroll
        for (int i = 0; i < (MT * BK) / 256; ++i) {
            int idx = tid + 256 * i;
            int r  = idx / BK;
            int kk = idx - r * BK;
            int p  = k0 + kk;
            float v = 0.f;
            if (r < LOUT && p < KDIM) v = xb[r * CIN + p];
            As[r][kk] = v;
        }
        // stage B tile (BK x NT)
        #pragma unroll
        for (int i = 0; i < (BK * NT) / 256; ++i) {
            int idx = tid + 256 * i;
            int kk = idx / NT;
            int c  = idx - kk * NT;
            Bs[kk][c] = wt[(size_t)(k0 + kk) * COUT + co0 + c];
        }
        __syncthreads();
        #pragma unroll
        for (int kk = 0; kk < BK; ++kk) {
            float4 bv = *(const float4*)&Bs[kk][tc * 4];
            float a[RPT];
            #pragma unroll
            for (int i = 0; i < RPT; ++i) a[i] = As[tr * RPT + i][kk];
            #pragma unroll
            for (int i = 0; i < RPT; ++i) {
                acc[i][0] += a[i] * bv.x;
                acc[i][1] += a[i] * bv.y;
                acc[i][2] += a[i] * bv.z;
                acc[i][3] += a[i] * bv.w;
            }
        }
        __syncthreads();
    }
    // per-thread max over its valid rows
    float m[4] = {-INFINITY, -INFINITY, -INFINITY, -INFINITY};
    #pragma unroll
    for (int i = 0; i < RPT; ++i) {
        int r = tr * RPT + i;
        if (r < LOUT) {
            #pragma unroll
            for (int j = 0; j < 4; ++j) m[j] = fmaxf(m[j], acc[i][j]);
        }
    }
    #pragma unroll
    for (int j = 0; j < 4; ++j) pmax[tr][tc * 4 + j] = m[j];
    __syncthreads();
    if (tid < NT) {
        float mm = pmax[0][tid];
        #pragma unroll
        for (int t = 1; t < 16; ++t) mm = fmaxf(mm, pmax[t][tid]);
        pooled[(size_t)bt * COUT + co0 + tid] = mm + bias[co0 + tid];
    }
}

// ---------------- highway: out = g*relu(x@WpT+bp) + (1-g)*x, g=sigmoid(x@WgT+bg) ----------------
template<int C, int OFF>
__global__ void highway_kernel(const float* __restrict__ pooled,
                               const float* __restrict__ WpT, const float* __restrict__ bp,
                               const float* __restrict__ WgT, const float* __restrict__ bg,
                               float* __restrict__ out) {
    int bt = blockIdx.x;
    int j  = threadIdx.x;
    __shared__ float xs[C];
    xs[j] = pooled[(size_t)bt * C + j];
    __syncthreads();
    float ap = bp[j], ag = bg[j];
    for (int c = 0; c < C; ++c) {
        float xv = xs[c];
        ap += xv * WpT[c * C + j];
        ag += xv * WgT[c * C + j];
    }
    float p = fmaxf(ap, 0.f);
    float g = 1.f / (1.f + expf(-ag));
    out[(size_t)bt * 448 + OFF + j] = g * p + (1.f - g) * xs[j];
}

// ---------------- masked LSTM, one block per sample ----------------
// x: (BTOT, 30, 20); WihT: (20,512); WhhT: (128,512); hout: (BTOT, 30, 128)
__global__ __launch_bounds__(512)
void lstm_kernel(const float* __restrict__ x, const int* __restrict__ lens,
                 const float* __restrict__ WihT, const float* __restrict__ WhhT,
                 const float* __restrict__ bih, const float* __restrict__ bhh,
                 float* __restrict__ hout) {
    int bt = blockIdx.x;
    int j  = threadIdx.x;   // 0..511 : gate row
    __shared__ float xs[WE_][EE];
    __shared__ __align__(16) float hs[HH];
    __shared__ float zs[512];

    for (int idx = j; idx < WE_ * EE; idx += 512)
        ((float*)xs)[idx] = x[(size_t)bt * WE_ * EE + idx];
    if (j < HH) hs[j] = 0.f;

    float wih[EE];
    #pragma unroll
    for (int e = 0; e < EE; ++e) wih[e] = WihT[e * 512 + j];
    float whh[HH];
    #pragma unroll
    for (int h = 0; h < HH; ++h) whh[h] = WhhT[h * 512 + j];
    float bj = bih[j] + bhh[j];
    float c_reg = 0.f;
    int len = lens[bt];
    __syncthreads();

    for (int t = 0; t < WE_; ++t) {
        float z = bj;
        #pragma unroll
        for (int e = 0; e < EE; ++e) z += wih[e] * xs[t][e];
        const float4* h4 = (const float4*)hs;
        #pragma unroll
        for (int q = 0; q < HH / 4; ++q) {
            float4 hv = h4[q];
            z += whh[4*q+0] * hv.x + whh[4*q+1] * hv.y
               + whh[4*q+2] * hv.z + whh[4*q+3] * hv.w;
        }
        zs[j] = z;
        __syncthreads();
        if (j < HH) {
            float zi = zs[j], zf = zs[HH + j], zg = zs[2*HH + j], zo = zs[3*HH + j];
            float si = 1.f / (1.f + expf(-zi));
            float sf = 1.f / (1.f + expf(-zf));
            float so = 1.f / (1.f + expf(-zo));
            float tg = tanhf(zg);
            float c2 = sf * c_reg + si * tg;
            float h2 = so * tanhf(c2);
            bool valid = (t < len);
            float hn = valid ? h2 : hs[j];
            c_reg    = valid ? c2 : c_reg;
            hout[((size_t)bt * WE_ + t) * HH + j] = valid ? h2 : 0.f;
            hs[j] = hn;
        }
        __syncthreads();
    }
}

// ---------------- launch ----------------
static inline int cdiv(int a, int b) { return (a + b - 1) / b; }

extern "C" void kernel_launch(void* const* d_in, const int* in_sizes, int n_in,
                              void* d_out, int out_size, void* d_ws, size_t ws_size,
                              hipStream_t stream) {
    const float* x_lin  = (const float*)d_in[0];
    const float* x_aco  = (const float*)d_in[1];
    const float* x_emo  = (const float*)d_in[2];
    const int*   wlen   = (const int*)  d_in[3];
    // d_in[4] = length : unused by reference
    const float* convL_w = (const float*)d_in[5];
    const float* convL_b = (const float*)d_in[6];
    const float* convA_w = (const float*)d_in[7];
    const float* convA_b = (const float*)d_in[8];
    const float* convE_w = (const float*)d_in[9];
    const float* convE_b = (const float*)d_in[10];
    const float* hwL_Wp = (const float*)d_in[11];
    const float* hwL_bp = (const float*)d_in[12];
    const float* hwL_Wg = (const float*)d_in[13];
    const float* hwL_bg = (const float*)d_in[14];
    const float* hwA_Wp = (const float*)d_in[15];
    const float* hwA_bp = (const float*)d_in[16];
    const float* hwA_Wg = (const float*)d_in[17];
    const float* hwA_bg = (const float*)d_in[18];
    const float* hwE_Wp = (const float*)d_in[19];
    const float* hwE_bp = (const float*)d_in[20];
    const float* hwE_Wg = (const float*)d_in[21];
    const float* hwE_bg = (const float*)d_in[22];
    const float* lstm_Wih = (const float*)d_in[23];
    const float* lstm_Whh = (const float*)d_in[24];
    const float* lstm_bih = (const float*)d_in[25];
    const float* lstm_bhh = (const float*)d_in[26];
    float* out = (float*)d_out;
    float* ws  = (float*)d_ws;

    // workspace layout (floats)
    size_t o = 0;
    float* wtA  = ws + o; o += (size_t)KPADA * CA;     // 2,531,328
    float* wtL  = ws + o; o += (size_t)KPADL * CL;     //   192,512
    float* wtE  = ws + o; o += (size_t)KPADE * CE;     //    24,576
    float* WpTL = ws + o; o += CL * CL;
    float* WgTL = ws + o; o += CL * CL;
    float* WpTA = ws + o; o += CA * CA;
    float* WgTA = ws + o; o += CA * CA;
    float* WpTE = ws + o; o += CE * CE;
    float* WgTE = ws + o; o += CE * CE;
    float* WihT = ws + o; o += 20 * 512;
    float* WhhT = ws + o; o += 128 * 512;
    float* hbuf = ws + o; o += (size_t)BTOT * WE_ * HH; // 5,898,240
    float* pL   = ws + o; o += (size_t)BTOT * CL;
    float* pA   = ws + o; o += (size_t)BTOT * CA;
    float* pE   = ws + o; o += (size_t)BTOT * CE;
    // total ~9.6M floats (~38.3 MB)

    // ---- weight prep ----
    prep_wt<EA, KA, CA, KPADA><<<cdiv(KPADA * CA, 256), 256, 0, stream>>>(convA_w, wtA);
    prep_wt<EL, KL, CL, KPADL><<<cdiv(KPADL * CL, 256), 256, 0, stream>>>(convL_w, wtL);
    prep_wt<HH, KE, CE, KPADE><<<cdiv(KPADE * CE, 256), 256, 0, stream>>>(convE_w, wtE);
    transpose_mat<<<cdiv(CL * CL, 256), 256, 0, stream>>>(hwL_Wp, WpTL, CL, CL);
    transpose_mat<<<cdiv(CL * CL, 256), 256, 0, stream>>>(hwL_Wg, WgTL, CL, CL);
    transpose_mat<<<cdiv(CA * CA, 256), 256, 0, stream>>>(hwA_Wp, WpTA, CA, CA);
    transpose_mat<<<cdiv(CA * CA, 256), 256, 0, stream>>>(hwA_Wg, WgTA, CA, CA);
    transpose_mat<<<cdiv(CE * CE, 256), 256, 0, stream>>>(hwE_Wp, WpTE, CE, CE);
    transpose_mat<<<cdiv(CE * CE, 256), 256, 0, stream>>>(hwE_Wg, WgTE, CE, CE);
    transpose_mat<<<cdiv(512 * 20, 256), 256, 0, stream>>>(lstm_Wih, WihT, 512, 20);
    transpose_mat<<<cdiv(512 * 128, 256), 256, 0, stream>>>(lstm_Whh, WhhT, 512, 128);

    // ---- LSTM (emotient) ----
    lstm_kernel<<<BTOT, 512, 0, stream>>>(x_emo, wlen, WihT, WhhT, lstm_bih, lstm_bhh, hbuf);

    // ---- convs + maxpool ----
    conv_max_kernel<EA, WA_, CA, KDIMA, KPADA, LOUTA, 48>
        <<<dim3(BTOT, CA / 64), 256, 0, stream>>>(x_aco, wtA, convA_b, pA);
    conv_max_kernel<EL, WL_, CL, KDIML, KPADL, LOUTL, 32>
        <<<dim3(BTOT, CL / 64), 256, 0, stream>>>(x_lin, wtL, convL_b, pL);
    conv_max_kernel<HH, WE_, CE, KDIME, KPADE, LOUTE, 32>
        <<<dim3(BTOT, CE / 64), 256, 0, stream>>>(hbuf, wtE, convE_b, pE);

    // ---- highways -> output concat (L:0..127, A:128..383, E:384..447) ----
    highway_kernel<CL, 0>  <<<BTOT, CL, 0, stream>>>(pL, WpTL, hwL_bp, WgTL, hwL_bg, out);
    highway_kernel<CA, 128><<<BTOT, CA, 0, stream>>>(pA, WpTA, hwA_bp, WgTA, hwA_bg, out);
    highway_kernel<CE, 384><<<BTOT, CE, 0, stream>>>(pE, WpTE, hwE_bp, WgTE, hwE_bg, out);
}

// Round 2
// 1245.012 us; speedup vs baseline: 6.1743x; 6.1743x over previous
//
#include <hip/hip_runtime.h>
#include <hip/hip_bf16.h>
#include <math.h>

// ---------------- problem dims (fixed by setup_inputs) ----------------
#define BTOT 1536            // B*T = 32*48
// linguistic
#define EL 300
#define WL_ 33
#define CL 128
#define LOUTL 29
#define KDIML 1500
// acoustic
#define EA 988
#define WA_ 50
#define CA 256
#define LOUTA 41
#define KDIMA 9880
// emotient
#define EE 20
#define WE_ 30
#define HH 128
#define CE 64
#define LOUTE 28
#define KDIME 384

typedef __attribute__((ext_vector_type(4))) float f32x4;
typedef __attribute__((ext_vector_type(8))) short short8;

// RNE float->bf16 (inputs finite)
__device__ inline unsigned short f2bf(float f) {
    unsigned int x = __float_as_uint(f);
    unsigned int r = (x + 0x7fffu + ((x >> 16) & 1u)) >> 16;
    return (unsigned short)r;
}

// ---------------- weight prep: conv w (Cout,Cin,K) -> bf16 wt[cout][p], p=k*Cin+c, zero-pad to KPAD ----------------
template<int CIN, int KW, int COUT, int KPAD>
__global__ void prep_wt_bf16(const float* __restrict__ w, unsigned short* __restrict__ wt) {
    int idx = blockIdx.x * blockDim.x + threadIdx.x;
    if (idx >= COUT * KPAD) return;
    int co = idx / KPAD;
    int p  = idx - co * KPAD;
    float v = 0.f;
    if (p < CIN * KW) {
        int c = p % CIN;
        int k = p / CIN;
        v = w[(co * CIN + c) * KW + k];
    }
    wt[idx] = f2bf(v);
}

// generic transpose: a (R,C) -> at (C,R)
__global__ void transpose_mat(const float* __restrict__ a, float* __restrict__ at, int R, int C) {
    int idx = blockIdx.x * blockDim.x + threadIdx.x;
    if (idx >= R * C) return;
    int r = idx / C, c = idx - r * C;
    at[c * R + r] = a[idx];
}

// ---------------- fused conv1d(GEMM, bf16 MFMA) + maxpool + bias ----------------
// x: (BTOT, WIN, CIN) fp32. Row rg=(bt*LOUT+l) of A = x[bt, l*CIN .. l*CIN+KDIM). wt: bf16 [COUT][KPAD] zero-padded.
// pooled[bt][co] = max_l conv(bt,l,co) + bias[co].
template<int NBT, int LOUT, int CIN, int WIN, int COUT, int KDIM, int KPAD>
__global__ __launch_bounds__(512, 2)
void conv_pool_kernel(const float* __restrict__ x, const unsigned short* __restrict__ wt,
                      const float* __restrict__ bias, float* __restrict__ pooled)
{
    constexpr int BMP   = 256;            // padded row tile
    constexpr int BN    = COUT;           // full N per block
    constexpr int NF    = BN / 64;        // per-wave 16-col frags (4/2/1)
    constexpr int NK    = KPAD / 32;      // K steps of 32
    constexpr int WINSZ = WIN * CIN;
    constexpr int MTOT  = BTOT * LOUT;
    constexpr int A_CH  = BMP * 4;        // 16B chunks (8 bf16 each) in A tile
    constexpr int B_CH  = BN * 4;
    constexpr int A_IT  = A_CH / 512;     // 2
    constexpr int B_IT  = (B_CH + 511) / 512;
    constexpr int BUFSZ = (BMP + BN) * 64;

    __shared__ __align__(16) char smem[65536];

    const int tid  = threadIdx.x;
    const int lane = tid & 63;
    const int wid  = tid >> 6;
    const int wm   = wid >> 2;        // 0..1
    const int wn   = wid & 3;         // 0..3
    const int lr   = lane & 15;
    const int lq   = lane >> 4;
    const int row0 = blockIdx.x * (NBT * LOUT);

    f32x4 acc[8][NF];
    #pragma unroll
    for (int i = 0; i < 8; ++i)
        #pragma unroll
        for (int j = 0; j < NF; ++j) acc[i][j] = (f32x4){0.f, 0.f, 0.f, 0.f};

    float4 areg[A_IT][2];
    int4   breg[B_IT];

    auto LOAD = [&](int kt) {
        const int k0 = kt * 32;
        #pragma unroll
        for (int i = 0; i < A_IT; ++i) {
            int idx = tid + i * 512;
            int r = idx >> 2, c4 = idx & 3;
            int rg = row0 + r; if (rg >= MTOT) rg = MTOT - 1;
            int bt = rg / LOUT;
            int l  = rg - bt * LOUT;
            int kc = k0 + c4 * 8;
            const float* src = x + (size_t)bt * WINSZ + l * CIN + kc;
            float4 v0 = {0.f,0.f,0.f,0.f}, v1 = {0.f,0.f,0.f,0.f};
            if (kc < KDIM)     v0 = *(const float4*)src;
            if (kc + 4 < KDIM) v1 = *(const float4*)(src + 4);
            areg[i][0] = v0; areg[i][1] = v1;
        }
        #pragma unroll
        for (int i = 0; i < B_IT; ++i) {
            int idx = tid + i * 512;
            if (B_CH % 512 == 0 || idx < B_CH) {
                int r = idx >> 2, c4 = idx & 3;
                breg[i] = *(const int4*)(wt + (size_t)r * KPAD + k0 + c4 * 8);
            }
        }
    };

    auto WRITE = [&](int buf) {
        char* sA = smem + buf * BUFSZ;
        char* sB = sA + BMP * 64;
        #pragma unroll
        for (int i = 0; i < A_IT; ++i) {
            int idx = tid + i * 512;
            int r = idx >> 2, c4 = idx & 3;
            union { short8 s; unsigned short u[8]; } o;
            float4 v0 = areg[i][0], v1 = areg[i][1];
            o.u[0] = f2bf(v0.x); o.u[1] = f2bf(v0.y); o.u[2] = f2bf(v0.z); o.u[3] = f2bf(v0.w);
            o.u[4] = f2bf(v1.x); o.u[5] = f2bf(v1.y); o.u[6] = f2bf(v1.z); o.u[7] = f2bf(v1.w);
            *(short8*)(sA + r * 64 + ((c4 * 16) ^ ((r & 3) << 4))) = o.s;
        }
        #pragma unroll
        for (int i = 0; i < B_IT; ++i) {
            int idx = tid + i * 512;
            if (B_CH % 512 == 0 || idx < B_CH) {
                int r = idx >> 2, c4 = idx & 3;
                *(int4*)(sB + r * 64 + ((c4 * 16) ^ ((r & 3) << 4))) = breg[i];
            }
        }
    };

    auto COMPUTE = [&](int buf) {
        const char* sA = smem + buf * BUFSZ;
        const char* sB = sA + BMP * 64;
        const int kb = lq * 16;           // byte offset of this lane's 8 bf16 k-slots
        short8 bfr[NF];
        #pragma unroll
        for (int nf = 0; nf < NF; ++nf) {
            int col = wn * (BN / 4) + nf * 16 + lr;
            bfr[nf] = *(const short8*)(sB + col * 64 + (kb ^ ((col & 3) << 4)));
        }
        #pragma unroll
        for (int mf = 0; mf < 8; ++mf) {
            int row = wm * 128 + mf * 16 + lr;
            short8 afr = *(const short8*)(sA + row * 64 + (kb ^ ((row & 3) << 4)));
            #pragma unroll
            for (int nf = 0; nf < NF; ++nf)
                acc[mf][nf] = __builtin_amdgcn_mfma_f32_16x16x32_bf16(afr, bfr[nf], acc[mf][nf], 0, 0, 0);
        }
    };

    LOAD(0); WRITE(0);
    __syncthreads();
    #pragma unroll 2
    for (int kt = 0; kt < NK; ++kt) {
        if (kt + 1 < NK) LOAD(kt + 1);
        COMPUTE(kt & 1);
        if (kt + 1 < NK) WRITE((kt + 1) & 1);
        __syncthreads();
    }

    // ---- fused maxpool epilogue: reuse smem as swizzled [256][64] f32 ----
    for (int nf = 0; nf < NF; ++nf) {
        #pragma unroll
        for (int mf = 0; mf < 8; ++mf) {
            int row = wm * 128 + mf * 16 + lq * 4;
            int cs  = wn * 16 + lr;
            f32x4 v = acc[mf][nf];
            #pragma unroll
            for (int r = 0; r < 4; ++r)
                *(float*)(smem + (row + r) * 256 + ((cs * 4) ^ (((row + r) & 7) << 4))) = v[r];
        }
        __syncthreads();
        if (tid < 64 * NBT) {
            int btl = tid >> 6, cs = tid & 63;
            int base = btl * LOUT;
            float m = *(const float*)(smem + base * 256 + ((cs * 4) ^ ((base & 7) << 4)));
            for (int l = 1; l < LOUT; ++l) {
                int rr = base + l;
                m = fmaxf(m, *(const float*)(smem + rr * 256 + ((cs * 4) ^ ((rr & 7) << 4))));
            }
            int col = (cs >> 4) * (BN / 4) + nf * 16 + (cs & 15);
            int bt  = blockIdx.x * NBT + btl;
            pooled[(size_t)bt * COUT + col] = m + bias[col];
        }
        __syncthreads();
    }
}

// ---------------- highway: out = g*relu(x@WpT+bp) + (1-g)*x ----------------
template<int C, int OFF>
__global__ void highway_kernel(const float* __restrict__ pooled,
                               const float* __restrict__ WpT, const float* __restrict__ bp,
                               const float* __restrict__ WgT, const float* __restrict__ bg,
                               float* __restrict__ out) {
    int bt = blockIdx.x;
    int j  = threadIdx.x;
    __shared__ float xs[C];
    xs[j] = pooled[(size_t)bt * C + j];
    __syncthreads();
    float ap = bp[j], ag = bg[j];
    for (int c = 0; c < C; ++c) {
        float xv = xs[c];
        ap += xv * WpT[c * C + j];
        ag += xv * WgT[c * C + j];
    }
    float p = fmaxf(ap, 0.f);
    float g = 1.f / (1.f + expf(-ag));
    out[(size_t)bt * 448 + OFF + j] = g * p + (1.f - g) * xs[j];
}

// ---------------- masked LSTM, one block per sample ----------------
__global__ __launch_bounds__(512)
void lstm_kernel(const float* __restrict__ x, const int* __restrict__ lens,
                 const float* __restrict__ WihT, const float* __restrict__ WhhT,
                 const float* __restrict__ bih, const float* __restrict__ bhh,
                 float* __restrict__ hout) {
    int bt = blockIdx.x;
    int j  = threadIdx.x;   // 0..511 : gate row
    __shared__ float xs[WE_][EE];
    __shared__ __align__(16) float hs[HH];
    __shared__ float zs[512];

    for (int idx = j; idx < WE_ * EE; idx += 512)
        ((float*)xs)[idx] = x[(size_t)bt * WE_ * EE + idx];
    if (j < HH) hs[j] = 0.f;

    float wih[EE];
    #pragma unroll
    for (int e = 0; e < EE; ++e) wih[e] = WihT[e * 512 + j];
    float whh[HH];
    #pragma unroll
    for (int h = 0; h < HH; ++h) whh[h] = WhhT[h * 512 + j];
    float bj = bih[j] + bhh[j];
    float c_reg = 0.f;
    int len = lens[bt];
    __syncthreads();

    for (int t = 0; t < WE_; ++t) {
        float z = bj;
        #pragma unroll
        for (int e = 0; e < EE; ++e) z += wih[e] * xs[t][e];
        const float4* h4 = (const float4*)hs;
        #pragma unroll
        for (int q = 0; q < HH / 4; ++q) {
            float4 hv = h4[q];
            z += whh[4*q+0] * hv.x + whh[4*q+1] * hv.y
               + whh[4*q+2] * hv.z + whh[4*q+3] * hv.w;
        }
        zs[j] = z;
        __syncthreads();
        if (j < HH) {
            float zi = zs[j], zf = zs[HH + j], zg = zs[2*HH + j], zo = zs[3*HH + j];
            float si = 1.f / (1.f + expf(-zi));
            float sf = 1.f / (1.f + expf(-zf));
            float so = 1.f / (1.f + expf(-zo));
            float tg = tanhf(zg);
            float c2 = sf * c_reg + si * tg;
            float h2 = so * tanhf(c2);
            bool valid = (t < len);
            float hn = valid ? h2 : hs[j];
            c_reg    = valid ? c2 : c_reg;
            hout[((size_t)bt * WE_ + t) * HH + j] = valid ? h2 : 0.f;
            hs[j] = hn;
        }
        __syncthreads();
    }
}

// ---------------- launch ----------------
static inline int cdiv(int a, int b) { return (a + b - 1) / b; }

extern "C" void kernel_launch(void* const* d_in, const int* in_sizes, int n_in,
                              void* d_out, int out_size, void* d_ws, size_t ws_size,
                              hipStream_t stream) {
    const float* x_lin  = (const float*)d_in[0];
    const float* x_aco  = (const float*)d_in[1];
    const float* x_emo  = (const float*)d_in[2];
    const int*   wlen   = (const int*)  d_in[3];
    const float* convL_w = (const float*)d_in[5];
    const float* convL_b = (const float*)d_in[6];
    const float* convA_w = (const float*)d_in[7];
    const float* convA_b = (const float*)d_in[8];
    const float* convE_w = (const float*)d_in[9];
    const float* convE_b = (const float*)d_in[10];
    const float* hwL_Wp = (const float*)d_in[11];
    const float* hwL_bp = (const float*)d_in[12];
    const float* hwL_Wg = (const float*)d_in[13];
    const float* hwL_bg = (const float*)d_in[14];
    const float* hwA_Wp = (const float*)d_in[15];
    const float* hwA_bp = (const float*)d_in[16];
    const float* hwA_Wg = (const float*)d_in[17];
    const float* hwA_bg = (const float*)d_in[18];
    const float* hwE_Wp = (const float*)d_in[19];
    const float* hwE_bp = (const float*)d_in[20];
    const float* hwE_Wg = (const float*)d_in[21];
    const float* hwE_bg = (const float*)d_in[22];
    const float* lstm_Wih = (const float*)d_in[23];
    const float* lstm_Whh = (const float*)d_in[24];
    const float* lstm_bih = (const float*)d_in[25];
    const float* lstm_bhh = (const float*)d_in[26];
    float* out = (float*)d_out;

    // KPADs
    constexpr int KPA = 9920;   // 310*32
    constexpr int KPL = 1536;   // 48*32
    constexpr int KPE = 384;    // 12*32

    // workspace carve (256B aligned)
    char* p = (char*)d_ws;
    auto alloc = [&](size_t bytes) { char* r = p; p += (bytes + 255) & ~(size_t)255; return r; };
    unsigned short* wtA = (unsigned short*)alloc((size_t)CA * KPA * 2);
    unsigned short* wtL = (unsigned short*)alloc((size_t)CL * KPL * 2);
    unsigned short* wtE = (unsigned short*)alloc((size_t)CE * KPE * 2);
    float* WpTL = (float*)alloc((size_t)CL * CL * 4);
    float* WgTL = (float*)alloc((size_t)CL * CL * 4);
    float* WpTA = (float*)alloc((size_t)CA * CA * 4);
    float* WgTA = (float*)alloc((size_t)CA * CA * 4);
    float* WpTE = (float*)alloc((size_t)CE * CE * 4);
    float* WgTE = (float*)alloc((size_t)CE * CE * 4);
    float* WihT = (float*)alloc((size_t)EE * 512 * 4);
    float* WhhT = (float*)alloc((size_t)HH * 512 * 4);
    float* hbuf = (float*)alloc((size_t)BTOT * WE_ * HH * 4);
    float* pL   = (float*)alloc((size_t)BTOT * CL * 4);
    float* pA   = (float*)alloc((size_t)BTOT * CA * 4);
    float* pE   = (float*)alloc((size_t)BTOT * CE * 4);

    // ---- weight prep ----
    prep_wt_bf16<EA, 10, CA, KPA><<<cdiv(CA * KPA, 256), 256, 0, stream>>>(convA_w, wtA);
    prep_wt_bf16<EL, 5,  CL, KPL><<<cdiv(CL * KPL, 256), 256, 0, stream>>>(convL_w, wtL);
    prep_wt_bf16<HH, 3,  CE, KPE><<<cdiv(CE * KPE, 256), 256, 0, stream>>>(convE_w, wtE);
    transpose_mat<<<cdiv(CL * CL, 256), 256, 0, stream>>>(hwL_Wp, WpTL, CL, CL);
    transpose_mat<<<cdiv(CL * CL, 256), 256, 0, stream>>>(hwL_Wg, WgTL, CL, CL);
    transpose_mat<<<cdiv(CA * CA, 256), 256, 0, stream>>>(hwA_Wp, WpTA, CA, CA);
    transpose_mat<<<cdiv(CA * CA, 256), 256, 0, stream>>>(hwA_Wg, WgTA, CA, CA);
    transpose_mat<<<cdiv(CE * CE, 256), 256, 0, stream>>>(hwE_Wp, WpTE, CE, CE);
    transpose_mat<<<cdiv(CE * CE, 256), 256, 0, stream>>>(hwE_Wg, WgTE, CE, CE);
    transpose_mat<<<cdiv(512 * EE, 256), 256, 0, stream>>>(lstm_Wih, WihT, 512, EE);
    transpose_mat<<<cdiv(512 * HH, 256), 256, 0, stream>>>(lstm_Whh, WhhT, 512, HH);

    // ---- LSTM (emotient) ----
    lstm_kernel<<<BTOT, 512, 0, stream>>>(x_emo, wlen, WihT, WhhT, lstm_bih, lstm_bhh, hbuf);

    // ---- fused conv+maxpool (bf16 MFMA GEMM) ----
    conv_pool_kernel<6, LOUTA, EA, WA_, CA, KDIMA, KPA>
        <<<BTOT / 6, 512, 0, stream>>>(x_aco, wtA, convA_b, pA);
    conv_pool_kernel<8, LOUTL, EL, WL_, CL, KDIML, KPL>
        <<<BTOT / 8, 512, 0, stream>>>(x_lin, wtL, convL_b, pL);
    conv_pool_kernel<8, LOUTE, HH, WE_, CE, KDIME, KPE>
        <<<BTOT / 8, 512, 0, stream>>>(hbuf, wtE, convE_b, pE);

    // ---- highways -> output concat (L:0..127, A:128..383, E:384..447) ----
    highway_kernel<CL, 0>  <<<BTOT, CL, 0, stream>>>(pL, WpTL, hwL_bp, WgTL, hwL_bg, out);
    highway_kernel<CA, 128><<<BTOT, CA, 0, stream>>>(pA, WpTA, hwA_bp, WgTA, hwA_bg, out);
    highway_kernel<CE, 384><<<BTOT, CE, 0, stream>>>(pE, WpTE, hwE_bp, WgTE, hwE_bg, out);
}

// Round 3
// 809.106 us; speedup vs baseline: 9.5007x; 1.5387x over previous
//
#include <hip/hip_runtime.h>
#include <hip/hip_bf16.h>
#include <math.h>

// ---------------- problem dims (fixed by setup_inputs) ----------------
#define BTOT 1536            // B*T = 32*48
// linguistic
#define EL 300
#define ELP 304              // padded CIN (16B-aligned bf16 rows)
#define WL_ 33
#define CL 128
#define LOUTL 29
#define KPL 1536             // 24*64
// acoustic
#define EA 988
#define EAP 992
#define WA_ 50
#define CA 256
#define LOUTA 41
#define KPA 9920             // 155*64 = 10*992
// emotient
#define EE 20
#define WE_ 30
#define HH 128
#define CE 64
#define LOUTE 28
#define KPE 384              // 6*64 = 3*128
// round-2 fallback K dims
#define KDIML 1500
#define KDIMA 9880
#define KDIME 384

typedef __attribute__((ext_vector_type(4))) float f32x4;
typedef __attribute__((ext_vector_type(8))) short short8;

// RNE float->bf16 (inputs finite)
__device__ inline unsigned short f2bf(float f) {
    unsigned int x = __float_as_uint(f);
    unsigned int r = (x + 0x7fffu + ((x >> 16) & 1u)) >> 16;
    return (unsigned short)r;
}

#define GLD16(gp, lp) __builtin_amdgcn_global_load_lds( \
    (const __attribute__((address_space(1))) void*)(gp), \
    (__attribute__((address_space(3))) void*)(lp), 16, 0, 0)

// ---------------- fp32 -> bf16 with CIN padding: in (rows, CIN) -> out (rows, CINP), pad zeros ----------------
template<int CIN, int CINP>
__global__ void cvt_pad_bf16(const float* __restrict__ in, unsigned short* __restrict__ out, int nrows) {
    constexpr int CH = CINP / 8;
    int stride = gridDim.x * blockDim.x;
    int total = nrows * CH;
    for (int idx = blockIdx.x * blockDim.x + threadIdx.x; idx < total; idx += stride) {
        int row = idx / CH, cc = idx - row * CH, c0 = cc * 8;
        const float* src = in + (size_t)row * CIN + c0;
        union { short8 s; unsigned short u[8]; } o;
        if (c0 + 8 <= CIN) {
            float4 v0 = *(const float4*)src;
            float4 v1 = *(const float4*)(src + 4);
            o.u[0]=f2bf(v0.x); o.u[1]=f2bf(v0.y); o.u[2]=f2bf(v0.z); o.u[3]=f2bf(v0.w);
            o.u[4]=f2bf(v1.x); o.u[5]=f2bf(v1.y); o.u[6]=f2bf(v1.z); o.u[7]=f2bf(v1.w);
        } else {
            #pragma unroll
            for (int j = 0; j < 8; ++j) o.u[j] = (c0 + j < CIN) ? f2bf(src[j]) : (unsigned short)0;
        }
        *(short8*)(out + (size_t)row * CINP + c0) = o.s;
    }
}

// ---------------- weight prep (new): w (Cout,Cin,K) -> bf16 wt[cout][p], p=k*CINP+c ----------------
template<int CIN, int CINP, int KW, int COUT, int KPAD>
__global__ void prep_wt_padded(const float* __restrict__ w, unsigned short* __restrict__ wt) {
    int idx = blockIdx.x * blockDim.x + threadIdx.x;
    if (idx >= COUT * KPAD) return;
    int co = idx / KPAD;
    int p  = idx - co * KPAD;
    int k  = p / CINP;
    int c  = p - k * CINP;
    float v = 0.f;
    if (k < KW && c < CIN) v = w[(co * CIN + c) * KW + k];
    wt[idx] = f2bf(v);
}

// ---------------- weight prep (round-2 fallback): wt[p][cout], p=k*CIN+c ----------------
template<int CIN, int KW, int COUT, int KPAD>
__global__ void prep_wt_r2(const float* __restrict__ w, unsigned short* __restrict__ wt) {
    int idx = blockIdx.x * blockDim.x + threadIdx.x;
    if (idx >= KPAD * COUT) return;
    int p  = idx / COUT;
    int co = idx - p * COUT;
    float v = 0.f;
    if (p < CIN * KW) {
        int c = p % CIN;
        int k = p / CIN;
        v = w[(co * CIN + c) * KW + k];
    }
    wt[idx] = f2bf(v);
}

// generic transpose: a (R,C) -> at (C,R)
__global__ void transpose_mat(const float* __restrict__ a, float* __restrict__ at, int R, int C) {
    int idx = blockIdx.x * blockDim.x + threadIdx.x;
    if (idx >= R * C) return;
    int r = idx / C, c = idx - r * C;
    at[c * R + r] = a[idx];
}

// ================= fused conv1d(GEMM bf16 MFMA, 4-phase pipelined) + maxpool + bias =================
// xb: bf16 (BTOT, WIN, CINP); row rg=(bt,l) of A = xb[bt, l*CINP .. l*CINP+KPAD) (contiguous).
// wt: bf16 [COUT][KPAD]. pooled[bt][co] = max_l conv + bias[co].
template<int NBT, int LOUT, int WIN, int CINP, int COUT, int KPAD>
__global__ __launch_bounds__(512, 2)
void conv_pool_mfma(const unsigned short* __restrict__ xb, const unsigned short* __restrict__ wt,
                    const float* __restrict__ bias, float* __restrict__ pooled)
{
    constexpr int BM     = 256;
    constexpr int NF     = COUT / 64;          // per-wave 16-col frags (4/2/1)
    constexpr int NK     = KPAD / 64;          // K-tiles of 64
    constexpr int ALOADS = 4;                  // 256*64*2B / (512*16B)
    constexpr int BLOADS = COUT * 64 * 2 / 8192;
    constexpr int ABYTES = BM * 128;           // A buf bytes (256 rows x 128B)
    constexpr int BUFB   = ABYTES + COUT * 128;
    constexpr int MVAL   = NBT * LOUT;         // valid rows per block

    __shared__ __align__(16) char smem[2 * BUFB];

    const int tid  = threadIdx.x;
    const int lane = tid & 63;
    const int wid  = tid >> 6;
    const int wm   = wid >> 2;        // 0..1
    const int wn   = wid & 3;         // 0..3
    const int lr   = lane & 15;
    const int lq   = lane >> 4;
    const int bx   = blockIdx.x;

    f32x4 acc[8][NF];
    #pragma unroll
    for (int i = 0; i < 8; ++i)
        #pragma unroll
        for (int j = 0; j < NF; ++j) acc[i][j] = (f32x4){0.f, 0.f, 0.f, 0.f};

    // stage tile ts (K range [ts*64, ts*64+64)) into smem+dstoff.
    // LDS dest linear; global source pre-XOR-swizzled so reads with XOR see A[row][k].
    auto STAGE = [&](int ts, int dstoff) {
        char* dbase = smem + dstoff;
        #pragma unroll
        for (int i = 0; i < ALOADS; ++i) {
            int c = i * 512 + wid * 64 + lane;
            int r = c >> 3;
            int o = (c & 7) << 4;
            int rv = (r < MVAL) ? r : (MVAL - 1);
            int btl = rv / LOUT;
            int l   = rv - btl * LOUT;
            const char* src = (const char*)xb
                + (((size_t)(bx * NBT + btl) * WIN + l) * CINP) * 2
                + (size_t)ts * 128 + (o ^ ((r & 7) << 4));
            GLD16(src, dbase + (i * 512 + wid * 64) * 16);
        }
        #pragma unroll
        for (int i = 0; i < BLOADS; ++i) {
            int c = i * 512 + wid * 64 + lane;
            int col = c >> 3;
            int o = (c & 7) << 4;
            const char* src = (const char*)wt + ((size_t)col * KPAD) * 2
                + (size_t)ts * 128 + (o ^ ((col & 7) << 4));
            GLD16(src, dbase + ABYTES + (i * 512 + wid * 64) * 16);
        }
    };

#define PHASE(MH, KS, DO_STAGE, DO_VM) do {                                        \
    const char* sA = smem + bufo;                                                  \
    const char* sB = sA + ABYTES;                                                  \
    const int kb  = (KS) * 64 + lq * 16;                                           \
    const int ra  = wm * 128 + (MH) * 64 + lr;                                     \
    const int sza = (ra & 7) << 4;                                                 \
    short8 a0 = *(const short8*)(sA + (size_t)(ra     ) * 128 + (kb ^ sza));       \
    short8 a1 = *(const short8*)(sA + (size_t)(ra + 16) * 128 + (kb ^ sza));       \
    short8 a2 = *(const short8*)(sA + (size_t)(ra + 32) * 128 + (kb ^ sza));       \
    short8 a3 = *(const short8*)(sA + (size_t)(ra + 48) * 128 + (kb ^ sza));       \
    const int cb  = wn * (16 * NF) + lr;                                           \
    const int szb = (cb & 7) << 4;                                                 \
    short8 bfr[NF];                                                                \
    _Pragma("unroll")                                                              \
    for (int nf = 0; nf < NF; ++nf)                                                \
        bfr[nf] = *(const short8*)(sB + (size_t)(cb + nf * 16) * 128 + (kb ^ szb));\
    if (DO_STAGE) STAGE(t + 1, bufo ^ BUFB);                                       \
    asm volatile("" ::: "memory");                                                 \
    __builtin_amdgcn_s_barrier();                                                  \
    __builtin_amdgcn_s_setprio(1);                                                 \
    _Pragma("unroll")                                                              \
    for (int nf = 0; nf < NF; ++nf) {                                              \
        acc[(MH)*4+0][nf] = __builtin_amdgcn_mfma_f32_16x16x32_bf16(a0, bfr[nf], acc[(MH)*4+0][nf], 0, 0, 0); \
        acc[(MH)*4+1][nf] = __builtin_amdgcn_mfma_f32_16x16x32_bf16(a1, bfr[nf], acc[(MH)*4+1][nf], 0, 0, 0); \
        acc[(MH)*4+2][nf] = __builtin_amdgcn_mfma_f32_16x16x32_bf16(a2, bfr[nf], acc[(MH)*4+2][nf], 0, 0, 0); \
        acc[(MH)*4+3][nf] = __builtin_amdgcn_mfma_f32_16x16x32_bf16(a3, bfr[nf], acc[(MH)*4+3][nf], 0, 0, 0); \
    }                                                                              \
    __builtin_amdgcn_s_setprio(0);                                                 \
    if (DO_VM) asm volatile("s_waitcnt vmcnt(0)" ::: "memory");                    \
    asm volatile("" ::: "memory");                                                 \
    __builtin_amdgcn_s_barrier();                                                  \
} while (0)

    STAGE(0, 0);
    asm volatile("s_waitcnt vmcnt(0)" ::: "memory");
    __builtin_amdgcn_s_barrier();

    for (int t = 0; t < NK; ++t) {
        const int bufo = (t & 1) * BUFB;
        const bool pf = (t + 1 < NK);
        PHASE(0, 0, pf,    false);
        PHASE(0, 1, false, false);
        PHASE(1, 0, false, false);
        PHASE(1, 1, false, pf);
    }
#undef PHASE
    __syncthreads();

    // ---- fused maxpool epilogue: reuse smem as swizzled [256][64] f32 ----
    for (int nf = 0; nf < NF; ++nf) {
        #pragma unroll
        for (int mf8 = 0; mf8 < 8; ++mf8) {
            int row = wm * 128 + (mf8 >> 2) * 64 + (mf8 & 3) * 16 + lq * 4;
            int cs  = wn * 16 + lr;
            f32x4 v = acc[mf8][nf];
            #pragma unroll
            for (int r = 0; r < 4; ++r)
                *(float*)(smem + (size_t)(row + r) * 256 + ((cs * 4) ^ (((row + r) & 7) << 4))) = v[r];
        }
        __syncthreads();
        if (tid < 64 * NBT) {
            int btl = tid >> 6, cs = tid & 63;
            int base = btl * LOUT;
            float m = *(const float*)(smem + (size_t)base * 256 + ((cs * 4) ^ ((base & 7) << 4)));
            for (int l = 1; l < LOUT; ++l) {
                int rr = base + l;
                m = fmaxf(m, *(const float*)(smem + (size_t)rr * 256 + ((cs * 4) ^ ((rr & 7) << 4))));
            }
            int col = (cs >> 4) * (16 * NF) + nf * 16 + (cs & 15);
            int bt  = bx * NBT + btl;
            pooled[(size_t)bt * COUT + col] = m + bias[col];
        }
        __syncthreads();
    }
}

// ================= round-2 fallback conv (fp32 in, reg-staged) =================
template<int CIN, int WIN, int COUT, int KDIM, int KPAD, int LOUT, int MT>
__global__ __launch_bounds__(512, 2)
void conv_pool_r2(const float* __restrict__ x, const unsigned short* __restrict__ wt,
                  const float* __restrict__ bias, float* __restrict__ pooled)
{
    constexpr int BMP   = 256;
    constexpr int BN    = COUT;
    constexpr int NF    = BN / 64;
    constexpr int NK    = KPAD / 32;
    constexpr int WINSZ = WIN * CIN;
    constexpr int MTOT  = BTOT * LOUT;
    constexpr int A_IT  = 2;
    constexpr int B_IT  = (BN * 4 + 511) / 512;
    constexpr int BUFSZ = (BMP + BN) * 64;
    __shared__ __align__(16) char smem[65536];
    const int tid  = threadIdx.x;
    const int lane = tid & 63;
    const int wid  = tid >> 6;
    const int wm   = wid >> 2;
    const int wn   = wid & 3;
    const int lr   = lane & 15;
    const int lq   = lane >> 4;
    const int row0 = blockIdx.x * (MT);
    f32x4 acc[8][NF];
    #pragma unroll
    for (int i = 0; i < 8; ++i)
        #pragma unroll
        for (int j = 0; j < NF; ++j) acc[i][j] = (f32x4){0.f,0.f,0.f,0.f};
    float4 areg[A_IT][2]; int4 breg[B_IT];
    auto LOAD = [&](int kt) {
        const int k0 = kt * 32;
        #pragma unroll
        for (int i = 0; i < A_IT; ++i) {
            int idx = tid + i * 512;
            int r = idx >> 2, c4 = idx & 3;
            int rg = row0 + r; if (rg >= MTOT) rg = MTOT - 1;
            int bt = rg / LOUT; int l = rg - bt * LOUT;
            int kc = k0 + c4 * 8;
            const float* src = x + (size_t)bt * WINSZ + l * CIN + kc;
            float4 v0 = {0,0,0,0}, v1 = {0,0,0,0};
            if (kc < KDIM) v0 = *(const float4*)src;
            if (kc + 4 < KDIM) v1 = *(const float4*)(src + 4);
            areg[i][0] = v0; areg[i][1] = v1;
        }
        #pragma unroll
        for (int i = 0; i < B_IT; ++i) {
            int idx = tid + i * 512;
            if ((BN * 4) % 512 == 0 || idx < BN * 4) {
                int r = idx >> 2, c4 = idx & 3;
                breg[i] = *(const int4*)(wt + (size_t)(k0 + c4 * 8) * 0 + (size_t)r * 0 + (size_t)(k0 + c4*8) * COUT + 0); // placeholder
            }
        }
    };
    (void)LOAD;
    // NOTE: fallback uses p-major wt [KPAD][COUT]
    auto LOAD2 = [&](int kt, const unsigned short* wtp) {
        const int k0 = kt * 32;
        #pragma unroll
        for (int i = 0; i < A_IT; ++i) {
            int idx = tid + i * 512;
            int r = idx >> 2, c4 = idx & 3;
            int rg = row0 + r; if (rg >= MTOT) rg = MTOT - 1;
            int bt = rg / LOUT; int l = rg - bt * LOUT;
            int kc = k0 + c4 * 8;
            const float* src = x + (size_t)bt * WINSZ + l * CIN + kc;
            float4 v0 = {0,0,0,0}, v1 = {0,0,0,0};
            if (kc < KDIM) v0 = *(const float4*)src;
            if (kc + 4 < KDIM) v1 = *(const float4*)(src + 4);
            areg[i][0] = v0; areg[i][1] = v1;
        }
        #pragma unroll
        for (int i = 0; i < B_IT; ++i) {
            int idx = tid + i * 512;
            if ((BN * 4) % 512 == 0 || idx < BN * 4) {
                int kk = idx >> (BN == 256 ? 6 : (BN == 128 ? 5 : 4));
                int cgroup = idx & ((BN / 4) - 1);
                breg[i] = *(const int4*)(wtp + (size_t)(k0 + kk * (128 / (BN / 8))) * 0); (void)kk; (void)cgroup;
            }
        }
    };
    (void)LOAD2;
    // Simplified correct fallback: scalar-ish staging (matches round-2 semantics)
    float4 areg2[2][2]; int4 breg2[2];
    auto LOADF = [&](int kt, const unsigned short* wtp) {
        const int k0 = kt * 32;
        #pragma unroll
        for (int i = 0; i < 2; ++i) {
            int idx = tid + i * 512;
            int r = idx >> 2, c4 = idx & 3;
            int rg = row0 + r; if (rg >= MTOT) rg = MTOT - 1;
            int bt = rg / LOUT; int l = rg - bt * LOUT;
            int kc = k0 + c4 * 8;
            const float* src = x + (size_t)bt * WINSZ + l * CIN + kc;
            float4 v0 = {0,0,0,0}, v1 = {0,0,0,0};
            if (kc < KDIM) v0 = *(const float4*)src;
            if (kc + 4 < KDIM) v1 = *(const float4*)(src + 4);
            areg2[i][0] = v0; areg2[i][1] = v1;
        }
        #pragma unroll
        for (int i = 0; i < 2; ++i) {
            int idx = tid + i * 512;
            if (idx < BN * 8) {
                int kk = idx / (BN / 4);
                int c8 = idx - kk * (BN / 4);
                breg2[i] = *(const int4*)(wtp + (size_t)(k0 + kk) * COUT + c8 * 8);
            }
        }
    };
    auto WRITEF = [&](int buf) {
        char* sA = smem + buf * BUFSZ;
        char* sB = sA + BMP * 64;
        #pragma unroll
        for (int i = 0; i < 2; ++i) {
            int idx = tid + i * 512;
            int r = idx >> 2, c4 = idx & 3;
            union { short8 s; unsigned short u[8]; } o;
            float4 v0 = areg2[i][0], v1 = areg2[i][1];
            o.u[0]=f2bf(v0.x); o.u[1]=f2bf(v0.y); o.u[2]=f2bf(v0.z); o.u[3]=f2bf(v0.w);
            o.u[4]=f2bf(v1.x); o.u[5]=f2bf(v1.y); o.u[6]=f2bf(v1.z); o.u[7]=f2bf(v1.w);
            *(short8*)(sA + r * 64 + ((c4 * 16) ^ (((r >> 1) & 3) << 4))) = o.s;
        }
        #pragma unroll
        for (int i = 0; i < 2; ++i) {
            int idx = tid + i * 512;
            if (idx < BN * 8) {
                int kk = idx / (BN / 4);
                int c8 = idx - kk * (BN / 4);
                // store as [col][k-slice 32]: col-major tile, col c8*8.., 8 cols of 2B*... keep row-major like main: [col][64B]
                unsigned short tmp[8];
                *(int4*)tmp = breg2[i];
                #pragma unroll
                for (int j = 0; j < 8; ++j) {
                    int col = c8 * 8 + j;
                    *(unsigned short*)(sB + col * 64 + ((kk * 2) ^ 0) * 1 + ((kk & 0x1f) * 2)) = tmp[j];
                }
            }
        }
    };
    (void)WRITEF; (void)LOADF; (void)breg; (void)areg;
    // The fallback path is unused when workspace is large (normal case). To keep it
    // simple and correct, do a direct (slow) computation: each thread-block pair
    // computes via fp32 accumulation in registers from global memory.
    // grid: (BTOT, COUT/64); block 512 -> each thread one (l-range, co) partial.
    // (This path mirrors round-1 performance; used only if ws_size is tiny.)
}

// Truly simple fallback conv (round-1 style, correct): one block per (bt, co-tile)
template<int CIN, int WIN, int COUT, int KDIM, int LOUT>
__global__ __launch_bounds__(256)
void conv_pool_simple(const float* __restrict__ x, const float* __restrict__ w,
                      const float* __restrict__ bias, float* __restrict__ pooled)
{
    // w: original (COUT, CIN, KW) layout, KW = KDIM/CIN
    constexpr int KW = KDIM / CIN;
    int bt = blockIdx.x;
    int co = blockIdx.y * 64 + (threadIdx.x & 63);
    int seg = threadIdx.x >> 6;   // 4 segments over l
    __shared__ float part[4][64];
    float m = -INFINITY;
    for (int l = seg; l < LOUT; l += 4) {
        float acc = 0.f;
        for (int k = 0; k < KW; ++k) {
            const float* xr = x + ((size_t)bt * WIN + l + k) * CIN;
            const float* wr = w + ((size_t)co * CIN) * KW + k;
            for (int c = 0; c < CIN; ++c) acc += xr[c] * wr[(size_t)c * KW];
        }
        m = fmaxf(m, acc);
    }
    part[seg][threadIdx.x & 63] = m;
    __syncthreads();
    if (threadIdx.x < 64) {
        float mm = fmaxf(fmaxf(part[0][threadIdx.x], part[1][threadIdx.x]),
                         fmaxf(part[2][threadIdx.x], part[3][threadIdx.x]));
        pooled[(size_t)bt * COUT + co] = mm + bias[co];
    }
}

// ---------------- highway ----------------
template<int C, int OFF>
__global__ void highway_kernel(const float* __restrict__ pooled,
                               const float* __restrict__ WpT, const float* __restrict__ bp,
                               const float* __restrict__ WgT, const float* __restrict__ bg,
                               float* __restrict__ out) {
    int bt = blockIdx.x;
    int j  = threadIdx.x;
    __shared__ float xs[C];
    xs[j] = pooled[(size_t)bt * C + j];
    __syncthreads();
    float ap = bp[j], ag = bg[j];
    for (int c = 0; c < C; ++c) {
        float xv = xs[c];
        ap += xv * WpT[c * C + j];
        ag += xv * WgT[c * C + j];
    }
    float p = fmaxf(ap, 0.f);
    float g = 1.f / (1.f + expf(-ag));
    out[(size_t)bt * 448 + OFF + j] = g * p + (1.f - g) * xs[j];
}

// ---------------- masked LSTM, one block per sample; OT: bf16 or f32 hout ----------------
template<bool BFOUT>
__global__ __launch_bounds__(512)
void lstm_kernel(const float* __restrict__ x, const int* __restrict__ lens,
                 const float* __restrict__ WihT, const float* __restrict__ WhhT,
                 const float* __restrict__ bih, const float* __restrict__ bhh,
                 void* __restrict__ hout_v) {
    int bt = blockIdx.x;
    int j  = threadIdx.x;
    __shared__ float xs[WE_][EE];
    __shared__ __align__(16) float hs[HH];
    __shared__ float zs[512];
    for (int idx = j; idx < WE_ * EE; idx += 512)
        ((float*)xs)[idx] = x[(size_t)bt * WE_ * EE + idx];
    if (j < HH) hs[j] = 0.f;
    float wih[EE];
    #pragma unroll
    for (int e = 0; e < EE; ++e) wih[e] = WihT[e * 512 + j];
    float whh[HH];
    #pragma unroll
    for (int h = 0; h < HH; ++h) whh[h] = WhhT[h * 512 + j];
    float bj = bih[j] + bhh[j];
    float c_reg = 0.f;
    int len = lens[bt];
    __syncthreads();
    for (int t = 0; t < WE_; ++t) {
        float z = bj;
        #pragma unroll
        for (int e = 0; e < EE; ++e) z += wih[e] * xs[t][e];
        const float4* h4 = (const float4*)hs;
        #pragma unroll
        for (int q = 0; q < HH / 4; ++q) {
            float4 hv = h4[q];
            z += whh[4*q+0] * hv.x + whh[4*q+1] * hv.y
               + whh[4*q+2] * hv.z + whh[4*q+3] * hv.w;
        }
        zs[j] = z;
        __syncthreads();
        if (j < HH) {
            float zi = zs[j], zf = zs[HH + j], zg = zs[2*HH + j], zo = zs[3*HH + j];
            float si = 1.f / (1.f + expf(-zi));
            float sf = 1.f / (1.f + expf(-zf));
            float so = 1.f / (1.f + expf(-zo));
            float tg = tanhf(zg);
            float c2 = sf * c_reg + si * tg;
            float h2 = so * tanhf(c2);
            bool valid = (t < len);
            float hn = valid ? h2 : hs[j];
            c_reg    = valid ? c2 : c_reg;
            float ov = valid ? h2 : 0.f;
            if (BFOUT) ((unsigned short*)hout_v)[((size_t)bt * WE_ + t) * HH + j] = f2bf(ov);
            else       ((float*)hout_v)[((size_t)bt * WE_ + t) * HH + j] = ov;
            hs[j] = hn;
        }
        __syncthreads();
    }
}

// ---------------- launch ----------------
static inline int cdiv(int a, int b) { return (a + b - 1) / b; }

extern "C" void kernel_launch(void* const* d_in, const int* in_sizes, int n_in,
                              void* d_out, int out_size, void* d_ws, size_t ws_size,
                              hipStream_t stream) {
    const float* x_lin  = (const float*)d_in[0];
    const float* x_aco  = (const float*)d_in[1];
    const float* x_emo  = (const float*)d_in[2];
    const int*   wlen   = (const int*)  d_in[3];
    const float* convL_w = (const float*)d_in[5];
    const float* convL_b = (const float*)d_in[6];
    const float* convA_w = (const float*)d_in[7];
    const float* convA_b = (const float*)d_in[8];
    const float* convE_w = (const float*)d_in[9];
    const float* convE_b = (const float*)d_in[10];
    const float* hwL_Wp = (const float*)d_in[11];
    const float* hwL_bp = (const float*)d_in[12];
    const float* hwL_Wg = (const float*)d_in[13];
    const float* hwL_bg = (const float*)d_in[14];
    const float* hwA_Wp = (const float*)d_in[15];
    const float* hwA_bp = (const float*)d_in[16];
    const float* hwA_Wg = (const float*)d_in[17];
    const float* hwA_bg = (const float*)d_in[18];
    const float* hwE_Wp = (const float*)d_in[19];
    const float* hwE_bp = (const float*)d_in[20];
    const float* hwE_Wg = (const float*)d_in[21];
    const float* hwE_bg = (const float*)d_in[22];
    const float* lstm_Wih = (const float*)d_in[23];
    const float* lstm_Whh = (const float*)d_in[24];
    const float* lstm_bih = (const float*)d_in[25];
    const float* lstm_bhh = (const float*)d_in[26];
    float* out = (float*)d_out;

    // ---- workspace carve (256B aligned), big buffers last ----
    char* p0 = (char*)d_ws;
    char* p = p0;
    auto alloc = [&](size_t bytes) { char* r = p; p += (bytes + 255) & ~(size_t)255; return r; };
    unsigned short* wtA = (unsigned short*)alloc((size_t)CA * KPA * 2);
    unsigned short* wtL = (unsigned short*)alloc((size_t)CL * KPL * 2);
    unsigned short* wtE = (unsigned short*)alloc((size_t)CE * KPE * 2);
    float* WpTL = (float*)alloc((size_t)CL * CL * 4);
    float* WgTL = (float*)alloc((size_t)CL * CL * 4);
    float* WpTA = (float*)alloc((size_t)CA * CA * 4);
    float* WgTA = (float*)alloc((size_t)CA * CA * 4);
    float* WpTE = (float*)alloc((size_t)CE * CE * 4);
    float* WgTE = (float*)alloc((size_t)CE * CE * 4);
    float* WihT = (float*)alloc((size_t)EE * 512 * 4);
    float* WhhT = (float*)alloc((size_t)HH * 512 * 4);
    void*  hbuf = (void*)alloc((size_t)BTOT * WE_ * HH * 4);   // fp32-sized; bf16 path uses half
    float* pL   = (float*)alloc((size_t)BTOT * CL * 4);
    float* pA   = (float*)alloc((size_t)BTOT * CA * 4);
    float* pE   = (float*)alloc((size_t)BTOT * CE * 4);
    unsigned short* xlin_p = (unsigned short*)alloc((size_t)BTOT * WL_ * ELP * 2 + 64);
    unsigned short* xaco_p = (unsigned short*)alloc((size_t)BTOT * WA_ * EAP * 2 + 64);
    size_t need = (size_t)(p - p0);
    bool big = ws_size >= need;

    // ---- shared preps ----
    transpose_mat<<<cdiv(CL * CL, 256), 256, 0, stream>>>(hwL_Wp, WpTL, CL, CL);
    transpose_mat<<<cdiv(CL * CL, 256), 256, 0, stream>>>(hwL_Wg, WgTL, CL, CL);
    transpose_mat<<<cdiv(CA * CA, 256), 256, 0, stream>>>(hwA_Wp, WpTA, CA, CA);
    transpose_mat<<<cdiv(CA * CA, 256), 256, 0, stream>>>(hwA_Wg, WgTA, CA, CA);
    transpose_mat<<<cdiv(CE * CE, 256), 256, 0, stream>>>(hwE_Wp, WpTE, CE, CE);
    transpose_mat<<<cdiv(CE * CE, 256), 256, 0, stream>>>(hwE_Wg, WgTE, CE, CE);
    transpose_mat<<<cdiv(512 * EE, 256), 256, 0, stream>>>(lstm_Wih, WihT, 512, EE);
    transpose_mat<<<cdiv(512 * HH, 256), 256, 0, stream>>>(lstm_Whh, WhhT, 512, HH);

    if (big) {
        // ---- bf16 padded copies of A operands ----
        cvt_pad_bf16<EA, EAP><<<2048, 256, 0, stream>>>(x_aco, xaco_p, BTOT * WA_);
        cvt_pad_bf16<EL, ELP><<<1024, 256, 0, stream>>>(x_lin, xlin_p, BTOT * WL_);
        // ---- weights (co-major, padded) ----
        prep_wt_padded<EA, EAP, 10, CA, KPA><<<cdiv(CA * KPA, 256), 256, 0, stream>>>(convA_w, wtA);
        prep_wt_padded<EL, ELP, 5,  CL, KPL><<<cdiv(CL * KPL, 256), 256, 0, stream>>>(convL_w, wtL);
        prep_wt_padded<HH, HH,  3,  CE, KPE><<<cdiv(CE * KPE, 256), 256, 0, stream>>>(convE_w, wtE);
        // ---- LSTM -> bf16 hbuf ----
        lstm_kernel<true><<<BTOT, 512, 0, stream>>>(x_emo, wlen, WihT, WhhT, lstm_bih, lstm_bhh, hbuf);
        // ---- pipelined MFMA convs ----
        conv_pool_mfma<6, LOUTA, WA_, EAP, CA, KPA>
            <<<BTOT / 6, 512, 0, stream>>>(xaco_p, wtA, convA_b, pA);
        conv_pool_mfma<8, LOUTL, WL_, ELP, CL, KPL>
            <<<BTOT / 8, 512, 0, stream>>>(xlin_p, wtL, convL_b, pL);
        conv_pool_mfma<8, LOUTE, WE_, HH, CE, KPE>
            <<<BTOT / 8, 512, 0, stream>>>((const unsigned short*)hbuf, wtE, convE_b, pE);
    } else {
        // ---- tiny-workspace fallback (slow but correct) ----
        lstm_kernel<false><<<BTOT, 512, 0, stream>>>(x_emo, wlen, WihT, WhhT, lstm_bih, lstm_bhh, hbuf);
        conv_pool_simple<EA, WA_, CA, KDIMA, LOUTA>
            <<<dim3(BTOT, CA / 64), 256, 0, stream>>>(x_aco, convA_w, convA_b, pA);
        conv_pool_simple<EL, WL_, CL, KDIML, LOUTL>
            <<<dim3(BTOT, CL / 64), 256, 0, stream>>>(x_lin, convL_w, convL_b, pL);
        conv_pool_simple<HH, WE_, CE, KDIME, LOUTE>
            <<<dim3(BTOT, CE / 64), 256, 0, stream>>>((const float*)hbuf, convE_w, convE_b, pE);
    }

    // ---- highways -> output concat (L:0..127, A:128..383, E:384..447) ----
    highway_kernel<CL, 0>  <<<BTOT, CL, 0, stream>>>(pL, WpTL, hwL_bp, WgTL, hwL_bg, out);
    highway_kernel<CA, 128><<<BTOT, CA, 0, stream>>>(pA, WpTA, hwA_bp, WgTA, hwA_bg, out);
    highway_kernel<CE, 384><<<BTOT, CE, 0, stream>>>(pE, WpTE, hwE_bp, WgTE, hwE_bg, out);
}

// Round 4
// 724.693 us; speedup vs baseline: 10.6073x; 1.1165x over previous
//
#include <hip/hip_runtime.h>
#include <hip/hip_bf16.h>
#include <math.h>

// ---------------- problem dims (fixed by setup_inputs) ----------------
#define BTOT 1536            // B*T = 32*48
// linguistic
#define EL 300
#define ELP 304
#define WL_ 33
#define CL 128
#define LOUTL 29
#define KPL 1536             // 24*64
// acoustic
#define EA 988
#define EAP 992
#define WA_ 50
#define CA 256
#define LOUTA 41
#define KPA 9920             // 155*64 = 10*992
// emotient
#define EE 20
#define WE_ 30
#define HH 128
#define CE 64
#define LOUTE 28
#define KPE 384              // 6*64 = 3*128
// fallback K dims
#define KDIML 1500
#define KDIMA 9880
#define KDIME 384

typedef __attribute__((ext_vector_type(4))) float f32x4;
typedef __attribute__((ext_vector_type(8))) short short8;

// RNE float->bf16 (inputs finite)
__device__ __forceinline__ unsigned short f2bf(float f) {
    unsigned int x = __float_as_uint(f);
    unsigned int r = (x + 0x7fffu + ((x >> 16) & 1u)) >> 16;
    return (unsigned short)r;
}

#define GLD16(gp, lp) __builtin_amdgcn_global_load_lds( \
    (const __attribute__((address_space(1))) void*)(gp), \
    (__attribute__((address_space(3))) void*)(lp), 16, 0, 0)

template<int N> __device__ __forceinline__ void vmwait() {
    if constexpr (N == 0) asm volatile("s_waitcnt vmcnt(0)" ::: "memory");
    else if constexpr (N == 2) asm volatile("s_waitcnt vmcnt(2)" ::: "memory");
    else if constexpr (N == 5) asm volatile("s_waitcnt vmcnt(5)" ::: "memory");
    else if constexpr (N == 6) asm volatile("s_waitcnt vmcnt(6)" ::: "memory");
    else if constexpr (N == 8) asm volatile("s_waitcnt vmcnt(8)" ::: "memory");
    else static_assert(N == 0 || N == 2 || N == 5 || N == 6 || N == 8, "add case");
}

// ================= fused small-prep kernel =================
// segments: 6 highway transposes, WihT, WhhT, [BIG: wtL, wtE, whh_bf]
__device__ __forceinline__ void tr_one(const float* a, float* at, int R, int C, int idx) {
    int r = idx / C, c = idx - r * C;
    at[c * R + r] = a[idx];
}
template<int CIN, int CINP, int KW, int COUT, int KPAD>
__device__ __forceinline__ void wt_one(const float* w, unsigned short* wt, int idx) {
    int co = idx / KPAD;
    int p  = idx - co * KPAD;
    int k  = p / CINP;
    int c  = p - k * CINP;
    float v = 0.f;
    if (k < KW && c < CIN) v = w[(co * CIN + c) * KW + k];
    wt[idx] = f2bf(v);
}
template<bool BIG>
__global__ void prep_small(const float* hwL_Wp, float* WpTL, const float* hwL_Wg, float* WgTL,
                           const float* hwA_Wp, float* WpTA, const float* hwA_Wg, float* WgTA,
                           const float* hwE_Wp, float* WpTE, const float* hwE_Wg, float* WgTE,
                           const float* lstm_Wih, float* WihT, const float* lstm_Whh, float* WhhT,
                           const float* convL_w, unsigned short* wtL,
                           const float* convE_w, unsigned short* wtE,
                           unsigned short* whh_bf) {
    constexpr int S1 = 16384, S2 = 16384, S3 = 65536, S4 = 65536, S5 = 4096, S6 = 4096;
    constexpr int S7 = 512 * 20, S8 = 512 * 128;
    constexpr int S9 = 128 * KPL, S10 = 64 * KPE, S11 = 512 * 128;
    constexpr int SMALL = S1 + S2 + S3 + S4 + S5 + S6 + S7 + S8;
    constexpr int TOTAL = BIG ? (SMALL + S9 + S10 + S11) : SMALL;
    int stride = gridDim.x * blockDim.x;
    for (int i = blockIdx.x * blockDim.x + threadIdx.x; i < TOTAL; i += stride) {
        int idx = i;
        if (idx < S1) { tr_one(hwL_Wp, WpTL, 128, 128, idx); continue; } idx -= S1;
        if (idx < S2) { tr_one(hwL_Wg, WgTL, 128, 128, idx); continue; } idx -= S2;
        if (idx < S3) { tr_one(hwA_Wp, WpTA, 256, 256, idx); continue; } idx -= S3;
        if (idx < S4) { tr_one(hwA_Wg, WgTA, 256, 256, idx); continue; } idx -= S4;
        if (idx < S5) { tr_one(hwE_Wp, WpTE, 64, 64, idx); continue; } idx -= S5;
        if (idx < S6) { tr_one(hwE_Wg, WgTE, 64, 64, idx); continue; } idx -= S6;
        if (idx < S7) { tr_one(lstm_Wih, WihT, 512, 20, idx); continue; } idx -= S7;
        if (idx < S8) { tr_one(lstm_Whh, WhhT, 512, 128, idx); continue; } idx -= S8;
        if constexpr (BIG) {
            if (idx < S9) { wt_one<EL, ELP, 5, CL, KPL>(convL_w, wtL, idx); continue; } idx -= S9;
            if (idx < S10) { wt_one<HH, HH, 3, CE, KPE>(convE_w, wtE, idx); continue; } idx -= S10;
            whh_bf[idx] = f2bf(lstm_Whh[idx]);
        }
    }
}

__global__ void prep_wtA(const float* __restrict__ w, unsigned short* __restrict__ wt) {
    int idx = blockIdx.x * blockDim.x + threadIdx.x;
    if (idx >= CA * KPA) return;
    wt_one<EA, EAP, 10, CA, KPA>(w, wt, idx);
}

// ---------------- fused fp32->bf16 pad convert for both big inputs ----------------
template<int CIN, int CINP>
__device__ __forceinline__ void cvt_chunk(const float* in, unsigned short* out, int idx) {
    constexpr int CH = CINP / 8;
    int row = idx / CH, c0 = (idx - row * CH) * 8;
    const float* src = in + (size_t)row * CIN + c0;
    union { short8 s; unsigned short u[8]; } o;
    if (c0 + 8 <= CIN) {
        float4 v0 = *(const float4*)src;
        float4 v1 = *(const float4*)(src + 4);
        o.u[0]=f2bf(v0.x); o.u[1]=f2bf(v0.y); o.u[2]=f2bf(v0.z); o.u[3]=f2bf(v0.w);
        o.u[4]=f2bf(v1.x); o.u[5]=f2bf(v1.y); o.u[6]=f2bf(v1.z); o.u[7]=f2bf(v1.w);
    } else {
        #pragma unroll
        for (int j = 0; j < 8; ++j) o.u[j] = (c0 + j < CIN) ? f2bf(src[j]) : (unsigned short)0;
    }
    *(short8*)(out + (size_t)row * CINP + c0) = o.s;
}
__global__ void cvt_both(const float* __restrict__ xa, const float* __restrict__ xl,
                         unsigned short* __restrict__ outa, unsigned short* __restrict__ outl) {
    constexpr int NAC = (BTOT * WA_) * (EAP / 8);
    constexpr int NLC = (BTOT * WL_) * (ELP / 8);
    int stride = gridDim.x * blockDim.x;
    for (int i = blockIdx.x * blockDim.x + threadIdx.x; i < NAC + NLC; i += stride) {
        if (i < NAC) cvt_chunk<EA, EAP>(xa, outa, i);
        else         cvt_chunk<EL, ELP>(xl, outl, i - NAC);
    }
}

// ================= fused conv1d (bf16 MFMA, counted-vmcnt pipeline) + maxpool + bias =================
template<int NBT, int LOUT, int WIN, int CINP, int COUT, int KPAD>
__global__ __launch_bounds__(512, 2)
void conv_pool_mfma(const unsigned short* __restrict__ xb, const unsigned short* __restrict__ wt,
                    const float* __restrict__ bias, float* __restrict__ pooled)
{
    constexpr int BM     = 256;
    constexpr int NF     = COUT / 64;          // per-wave 16-col frags (4/2/1)
    constexpr int NK     = KPAD / 64;          // K-tiles of 64
    constexpr int BLOADS = COUT * 64 * 2 / 8192;
    constexpr int ABYTES = BM * 128;
    constexpr int BUFB   = ABYTES + COUT * 128;
    constexpr int MVAL   = NBT * LOUT;

    __shared__ __align__(16) char smem[2 * BUFB];

    const int tid  = threadIdx.x;
    const int lane = tid & 63;
    const int wid  = tid >> 6;
    const int wm   = wid >> 2;        // 0..1
    const int wn   = wid & 3;         // 0..3
    const int lr   = lane & 15;
    const int lq   = lane >> 4;
    const int bx   = blockIdx.x;

    f32x4 acc[8][NF];
    #pragma unroll
    for (int i = 0; i < 8; ++i)
        #pragma unroll
        for (int j = 0; j < NF; ++j) acc[i][j] = (f32x4){0.f, 0.f, 0.f, 0.f};

    // B-cols staged first, then A-half0 (rows 0-127), then A-half1 (rows 128-255).
    auto STAGE_B = [&](int ts, char* dbase) {
        #pragma unroll
        for (int i = 0; i < BLOADS; ++i) {
            int c = i * 512 + wid * 64 + lane;
            int col = c >> 3;
            int o = (c & 7) << 4;
            const char* src = (const char*)wt + ((size_t)col * KPAD) * 2
                + (size_t)ts * 128 + (o ^ ((col & 7) << 4));
            GLD16(src, dbase + ABYTES + (i * 512 + wid * 64) * 16);
        }
    };
    auto STAGE_A = [&](int ts, char* dbase, int i0) {
        #pragma unroll
        for (int ii = 0; ii < 2; ++ii) {
            int i = i0 + ii;
            int c = i * 512 + wid * 64 + lane;
            int r = c >> 3;
            int o = (c & 7) << 4;
            int rv = (r < MVAL) ? r : (MVAL - 1);
            int btl = rv / LOUT;
            int l   = rv - btl * LOUT;
            const char* src = (const char*)xb
                + (((size_t)(bx * NBT + btl) * WIN + l) * CINP) * 2
                + (size_t)ts * 128 + (o ^ ((r & 7) << 4));
            GLD16(src, dbase + (i * 512 + wid * 64) * 16);
        }
    };

    // phase (MH=global row half, KS=k half): reads A rows MH*128+wm*64.., B all cols
#define PHASE(MH, KS, STAGESTMT, WAITSTMT) do {                                    \
    const char* sA = smem + bufo;                                                  \
    const char* sB = sA + ABYTES;                                                  \
    const int kb  = (KS) * 64 + lq * 16;                                           \
    const int ra  = (MH) * 128 + wm * 64 + lr;                                     \
    const int sza = (ra & 7) << 4;                                                 \
    short8 a0 = *(const short8*)(sA + (size_t)(ra     ) * 128 + (kb ^ sza));       \
    short8 a1 = *(const short8*)(sA + (size_t)(ra + 16) * 128 + (kb ^ sza));       \
    short8 a2 = *(const short8*)(sA + (size_t)(ra + 32) * 128 + (kb ^ sza));       \
    short8 a3 = *(const short8*)(sA + (size_t)(ra + 48) * 128 + (kb ^ sza));       \
    const int cb  = wn * (16 * NF) + lr;                                           \
    const int szb = (cb & 7) << 4;                                                 \
    short8 bfr[NF];                                                                \
    _Pragma("unroll")                                                              \
    for (int nf = 0; nf < NF; ++nf)                                                \
        bfr[nf] = *(const short8*)(sB + (size_t)(cb + nf * 16) * 128 + (kb ^ szb));\
    STAGESTMT;                                                                     \
    asm volatile("" ::: "memory");                                                 \
    __builtin_amdgcn_s_barrier();                                                  \
    asm volatile("s_waitcnt lgkmcnt(0)" ::: "memory");                             \
    __builtin_amdgcn_sched_barrier(0);                                             \
    __builtin_amdgcn_s_setprio(1);                                                 \
    _Pragma("unroll")                                                              \
    for (int nf = 0; nf < NF; ++nf) {                                              \
        acc[(MH)*4+0][nf] = __builtin_amdgcn_mfma_f32_16x16x32_bf16(a0, bfr[nf], acc[(MH)*4+0][nf], 0, 0, 0); \
        acc[(MH)*4+1][nf] = __builtin_amdgcn_mfma_f32_16x16x32_bf16(a1, bfr[nf], acc[(MH)*4+1][nf], 0, 0, 0); \
        acc[(MH)*4+2][nf] = __builtin_amdgcn_mfma_f32_16x16x32_bf16(a2, bfr[nf], acc[(MH)*4+2][nf], 0, 0, 0); \
        acc[(MH)*4+3][nf] = __builtin_amdgcn_mfma_f32_16x16x32_bf16(a3, bfr[nf], acc[(MH)*4+3][nf], 0, 0, 0); \
    }                                                                              \
    __builtin_amdgcn_s_setprio(0);                                                 \
    WAITSTMT;                                                                      \
    asm volatile("" ::: "memory");                                                 \
    __builtin_amdgcn_s_barrier();                                                  \
} while (0)

    STAGE_B(0, smem); STAGE_A(0, smem, 0); STAGE_A(0, smem, 2);
    vmwait<0>();
    __builtin_amdgcn_s_barrier();

    for (int t = 0; t < NK; ++t) {
        const int bufo = (t & 1) * BUFB;
        char* nb = smem + (bufo ^ BUFB);
        const bool pf = (t + 1 < NK);
        PHASE(0, 0, { if (pf) { STAGE_B(t + 1, nb); STAGE_A(t + 1, nb, 0); } }, {});
        PHASE(0, 1, { if (pf) STAGE_A(t + 1, nb, 2); },
                    { if (pf) vmwait<BLOADS + 4>(); else vmwait<0>(); });
        PHASE(1, 0, {}, {});
        PHASE(1, 1, {}, { if (pf) vmwait<2>(); else vmwait<0>(); });
    }
#undef PHASE
    __syncthreads();

    // ---- fused maxpool epilogue: reuse smem as swizzled [256][64] f32 ----
    for (int nf = 0; nf < NF; ++nf) {
        #pragma unroll
        for (int mf8 = 0; mf8 < 8; ++mf8) {
            int row = (mf8 >> 2) * 128 + wm * 64 + (mf8 & 3) * 16 + lq * 4;
            int cs  = wn * 16 + lr;
            f32x4 v = acc[mf8][nf];
            #pragma unroll
            for (int r = 0; r < 4; ++r)
                *(float*)(smem + (size_t)(row + r) * 256 + ((cs * 4) ^ (((row + r) & 7) << 4))) = v[r];
        }
        __syncthreads();
        if (tid < 64 * NBT) {
            int btl = tid >> 6, cs = tid & 63;
            int base = btl * LOUT;
            float m = *(const float*)(smem + (size_t)base * 256 + ((cs * 4) ^ ((base & 7) << 4)));
            for (int l = 1; l < LOUT; ++l) {
                int rr = base + l;
                m = fmaxf(m, *(const float*)(smem + (size_t)rr * 256 + ((cs * 4) ^ ((rr & 7) << 4))));
            }
            int col = (cs >> 4) * (16 * NF) + nf * 16 + (cs & 15);
            int bt  = bx * NBT + btl;
            pooled[(size_t)bt * COUT + col] = m + bias[col];
        }
        __syncthreads();
    }
}

// ================= zx = X @ Wih^T  (46080 x 512, K=20), f32 =================
__global__ __launch_bounds__(256)
void zx_kernel(const float* __restrict__ x, const float* __restrict__ Wih, float* __restrict__ zx) {
    __shared__ float xs[2][EE];
    int r0 = blockIdx.x * 2;
    int tid = threadIdx.x;
    if (tid < 2 * EE) xs[tid / EE][tid % EE] = x[(size_t)(r0 + tid / EE) * EE + tid % EE];
    __syncthreads();
    int half = tid >> 7;
    int c0 = (tid & 127) * 4;
    const float* xr = xs[half];
    float a0 = 0.f, a1 = 0.f, a2 = 0.f, a3 = 0.f;
    #pragma unroll
    for (int e = 0; e < EE; ++e) {
        float xv = xr[e];
        a0 += xv * Wih[(size_t)(c0 + 0) * EE + e];
        a1 += xv * Wih[(size_t)(c0 + 1) * EE + e];
        a2 += xv * Wih[(size_t)(c0 + 2) * EE + e];
        a3 += xv * Wih[(size_t)(c0 + 3) * EE + e];
    }
    float4 o = {a0, a1, a2, a3};
    *(float4*)&zx[(size_t)(r0 + half) * 512 + c0] = o;
}

// ================= masked LSTM via MFMA: 16 samples/block, 96 blocks =================
// zx: (46080, 512) f32 precomputed x@Wih^T; whh_bf: (512,128) bf16 row-major.
// hbuf out: (BTOT, 30, 128) bf16. h recurrence carried in bf16, c in f32.
__global__ __launch_bounds__(512, 1)
void lstm_mfma(const float* __restrict__ zx, const unsigned short* __restrict__ whh_bf,
               const float* __restrict__ bih, const float* __restrict__ bhh,
               const int* __restrict__ lens, unsigned short* __restrict__ hbuf)
{
    __shared__ __align__(16) unsigned short hout_s[16 * WE_ * HH];   // 120 KB
    __shared__ __align__(16) char h_s[2 * 16 * HH * 2];              // 8 KB, swizzled bf16

    const int tid  = threadIdx.x;
    const int w    = tid >> 6;
    const int lane = tid & 63;
    const int lr   = lane & 15;
    const int lq   = lane >> 4;
    const int s0   = blockIdx.x * 16;

    // B-frags (Whh) resident in registers: col = g*128 + w*16 + lr, k = kt*32 + lq*8
    short8 bfr[4][4];
    float bj[4];
    #pragma unroll
    for (int g = 0; g < 4; ++g) {
        int col = g * 128 + w * 16 + lr;
        #pragma unroll
        for (int kt = 0; kt < 4; ++kt)
            bfr[g][kt] = *(const short8*)(whh_bf + (size_t)col * 128 + kt * 32 + lq * 8);
        bj[g] = bih[col] + bhh[col];
    }
    int len4[4];
    #pragma unroll
    for (int j = 0; j < 4; ++j) len4[j] = lens[s0 + lq * 4 + j];

    for (int i = tid; i < 2048; i += 512) ((unsigned int*)h_s)[i] = 0u;
    float c_prev[4] = {0.f, 0.f, 0.f, 0.f};
    unsigned short hb_prev[4] = {0, 0, 0, 0};
    const int c = w * 16 + lr;
    __syncthreads();

    for (int t = 0; t < WE_; ++t) {
        const char* hsr = h_s + (t & 1) * 4096;
        char* hsw = h_s + (((t & 1) ^ 1)) * 4096;
        // A-frags: h[sample=lr][k], swizzled
        short8 af[4];
        #pragma unroll
        for (int kt = 0; kt < 4; ++kt)
            af[kt] = *(const short8*)(hsr + ((lr * 256 + kt * 64 + lq * 16) ^ ((lr & 7) << 4)));
        f32x4 acc[4];
        #pragma unroll
        for (int g = 0; g < 4; ++g) acc[g] = (f32x4){0.f, 0.f, 0.f, 0.f};
        #pragma unroll
        for (int kt = 0; kt < 4; ++kt)
            #pragma unroll
            for (int g = 0; g < 4; ++g)
                acc[g] = __builtin_amdgcn_mfma_f32_16x16x32_bf16(af[kt], bfr[g][kt], acc[g], 0, 0, 0);
        #pragma unroll
        for (int j = 0; j < 4; ++j) {
            int s = lq * 4 + j;
            size_t zr = ((size_t)(s0 + s) * WE_ + t) * 512;
            float zi = acc[0][j] + zx[zr + c]           + bj[0];
            float zf = acc[1][j] + zx[zr + 128 + c]     + bj[1];
            float zg = acc[2][j] + zx[zr + 256 + c]     + bj[2];
            float zo = acc[3][j] + zx[zr + 384 + c]     + bj[3];
            float si = 1.f / (1.f + expf(-zi));
            float sf = 1.f / (1.f + expf(-zf));
            float so = 1.f / (1.f + expf(-zo));
            float tg = tanhf(zg);
            float c2 = sf * c_prev[j] + si * tg;
            float h2 = so * tanhf(c2);
            bool valid = (t < len4[j]);
            c_prev[j] = valid ? c2 : c_prev[j];
            unsigned short h2b = f2bf(h2);
            unsigned short hn = valid ? h2b : hb_prev[j];
            hb_prev[j] = hn;
            *(unsigned short*)(hsw + (((s * HH + c) * 2) ^ ((s & 7) << 4))) = hn;
            hout_s[(s * WE_ + t) * HH + c] = valid ? h2b : (unsigned short)0;
        }
        __syncthreads();
    }
    // coalesced dump to global
    int4* dst = (int4*)(hbuf + (size_t)s0 * WE_ * HH);
    const int4* srcp = (const int4*)hout_s;
    for (int i = tid; i < (16 * WE_ * HH) / 8; i += 512) dst[i] = srcp[i];
}

// ---------------- highway ----------------
template<int C, int OFF>
__global__ void highway_kernel(const float* __restrict__ pooled,
                               const float* __restrict__ WpT, const float* __restrict__ bp,
                               const float* __restrict__ WgT, const float* __restrict__ bg,
                               float* __restrict__ out) {
    int bt = blockIdx.x;
    int j  = threadIdx.x;
    __shared__ float xs[C];
    xs[j] = pooled[(size_t)bt * C + j];
    __syncthreads();
    float ap = bp[j], ag = bg[j];
    for (int cc = 0; cc < C; ++cc) {
        float xv = xs[cc];
        ap += xv * WpT[cc * C + j];
        ag += xv * WgT[cc * C + j];
    }
    float p = fmaxf(ap, 0.f);
    float g = 1.f / (1.f + expf(-ag));
    out[(size_t)bt * 448 + OFF + j] = g * p + (1.f - g) * xs[j];
}

// ================= fallback path (tiny workspace): slow but correct =================
__global__ __launch_bounds__(512)
void lstm_kernel_f32(const float* __restrict__ x, const int* __restrict__ lens,
                     const float* __restrict__ WihT, const float* __restrict__ WhhT,
                     const float* __restrict__ bih, const float* __restrict__ bhh,
                     float* __restrict__ hout) {
    int bt = blockIdx.x;
    int j  = threadIdx.x;
    __shared__ float xs[WE_][EE];
    __shared__ __align__(16) float hs[HH];
    __shared__ float zs[512];
    for (int idx = j; idx < WE_ * EE; idx += 512)
        ((float*)xs)[idx] = x[(size_t)bt * WE_ * EE + idx];
    if (j < HH) hs[j] = 0.f;
    float wih[EE];
    #pragma unroll
    for (int e = 0; e < EE; ++e) wih[e] = WihT[e * 512 + j];
    float whh[HH];
    #pragma unroll
    for (int h = 0; h < HH; ++h) whh[h] = WhhT[h * 512 + j];
    float bjv = bih[j] + bhh[j];
    float c_reg = 0.f;
    int len = lens[bt];
    __syncthreads();
    for (int t = 0; t < WE_; ++t) {
        float z = bjv;
        #pragma unroll
        for (int e = 0; e < EE; ++e) z += wih[e] * xs[t][e];
        const float4* h4 = (const float4*)hs;
        #pragma unroll
        for (int q = 0; q < HH / 4; ++q) {
            float4 hv = h4[q];
            z += whh[4*q+0] * hv.x + whh[4*q+1] * hv.y
               + whh[4*q+2] * hv.z + whh[4*q+3] * hv.w;
        }
        zs[j] = z;
        __syncthreads();
        if (j < HH) {
            float zi = zs[j], zf = zs[HH + j], zg = zs[2*HH + j], zo = zs[3*HH + j];
            float si = 1.f / (1.f + expf(-zi));
            float sf = 1.f / (1.f + expf(-zf));
            float so = 1.f / (1.f + expf(-zo));
            float tg = tanhf(zg);
            float c2 = sf * c_reg + si * tg;
            float h2 = so * tanhf(c2);
            bool valid = (t < len);
            float hn = valid ? h2 : hs[j];
            c_reg    = valid ? c2 : c_reg;
            hout[((size_t)bt * WE_ + t) * HH + j] = valid ? h2 : 0.f;
            hs[j] = hn;
        }
        __syncthreads();
    }
}

template<int CIN, int WIN, int COUT, int KDIM, int LOUT>
__global__ __launch_bounds__(256)
void conv_pool_simple(const float* __restrict__ x, const float* __restrict__ w,
                      const float* __restrict__ bias, float* __restrict__ pooled)
{
    constexpr int KW = KDIM / CIN;
    int bt = blockIdx.x;
    int co = blockIdx.y * 64 + (threadIdx.x & 63);
    int seg = threadIdx.x >> 6;
    __shared__ float part[4][64];
    float m = -INFINITY;
    for (int l = seg; l < LOUT; l += 4) {
        float acc = 0.f;
        for (int k = 0; k < KW; ++k) {
            const float* xr = x + ((size_t)bt * WIN + l + k) * CIN;
            const float* wr = w + ((size_t)co * CIN) * KW + k;
            for (int cc = 0; cc < CIN; ++cc) acc += xr[cc] * wr[(size_t)cc * KW];
        }
        m = fmaxf(m, acc);
    }
    part[seg][threadIdx.x & 63] = m;
    __syncthreads();
    if (threadIdx.x < 64) {
        float mm = fmaxf(fmaxf(part[0][threadIdx.x], part[1][threadIdx.x]),
                         fmaxf(part[2][threadIdx.x], part[3][threadIdx.x]));
        pooled[(size_t)bt * COUT + co] = mm + bias[co];
    }
}

// ---------------- launch ----------------
static inline int cdiv(int a, int b) { return (a + b - 1) / b; }

extern "C" void kernel_launch(void* const* d_in, const int* in_sizes, int n_in,
                              void* d_out, int out_size, void* d_ws, size_t ws_size,
                              hipStream_t stream) {
    const float* x_lin  = (const float*)d_in[0];
    const float* x_aco  = (const float*)d_in[1];
    const float* x_emo  = (const float*)d_in[2];
    const int*   wlen   = (const int*)  d_in[3];
    const float* convL_w = (const float*)d_in[5];
    const float* convL_b = (const float*)d_in[6];
    const float* convA_w = (const float*)d_in[7];
    const float* convA_b = (const float*)d_in[8];
    const float* convE_w = (const float*)d_in[9];
    const float* convE_b = (const float*)d_in[10];
    const float* hwL_Wp = (const float*)d_in[11];
    const float* hwL_bp = (const float*)d_in[12];
    const float* hwL_Wg = (const float*)d_in[13];
    const float* hwL_bg = (const float*)d_in[14];
    const float* hwA_Wp = (const float*)d_in[15];
    const float* hwA_bp = (const float*)d_in[16];
    const float* hwA_Wg = (const float*)d_in[17];
    const float* hwA_bg = (const float*)d_in[18];
    const float* hwE_Wp = (const float*)d_in[19];
    const float* hwE_bp = (const float*)d_in[20];
    const float* hwE_Wg = (const float*)d_in[21];
    const float* hwE_bg = (const float*)d_in[22];
    const float* lstm_Wih = (const float*)d_in[23];
    const float* lstm_Whh = (const float*)d_in[24];
    const float* lstm_bih = (const float*)d_in[25];
    const float* lstm_bhh = (const float*)d_in[26];
    float* out = (float*)d_out;

    // ---- workspace carve (256B aligned): small/essential first, big last ----
    char* p0 = (char*)d_ws;
    char* p = p0;
    auto alloc = [&](size_t bytes) { char* r = p; p += (bytes + 255) & ~(size_t)255; return r; };
    float* WpTL = (float*)alloc((size_t)CL * CL * 4);
    float* WgTL = (float*)alloc((size_t)CL * CL * 4);
    float* WpTA = (float*)alloc((size_t)CA * CA * 4);
    float* WgTA = (float*)alloc((size_t)CA * CA * 4);
    float* WpTE = (float*)alloc((size_t)CE * CE * 4);
    float* WgTE = (float*)alloc((size_t)CE * CE * 4);
    float* WihT = (float*)alloc((size_t)EE * 512 * 4);
    float* WhhT = (float*)alloc((size_t)HH * 512 * 4);
    unsigned short* whh_bf = (unsigned short*)alloc((size_t)512 * 128 * 2);
    void*  hbuf = (void*)alloc((size_t)BTOT * WE_ * HH * 4);    // f32-sized; fast path uses bf16 half
    float* pL   = (float*)alloc((size_t)BTOT * CL * 4);
    float* pA   = (float*)alloc((size_t)BTOT * CA * 4);
    float* pE   = (float*)alloc((size_t)BTOT * CE * 4);
    // big buffers
    unsigned short* wtA = (unsigned short*)alloc((size_t)CA * KPA * 2);
    unsigned short* wtL = (unsigned short*)alloc((size_t)CL * KPL * 2);
    unsigned short* wtE = (unsigned short*)alloc((size_t)CE * KPE * 2);
    unsigned short* xlin_p = (unsigned short*)alloc((size_t)BTOT * WL_ * ELP * 2 + 64);
    unsigned short* xaco_p = (unsigned short*)alloc((size_t)BTOT * WA_ * EAP * 2 + 64);
    size_t need = (size_t)(p - p0);
    bool big = ws_size >= need;
    // zx (46080 x 512 f32 = 94.4 MB) aliases xaco_p (152 MB): dead before cvt_both runs
    float* zx = (float*)xaco_p;

    if (big) {
        prep_small<true><<<2088, 256, 0, stream>>>(hwL_Wp, WpTL, hwL_Wg, WgTL, hwA_Wp, WpTA, hwA_Wg, WgTA,
                                                   hwE_Wp, WpTE, hwE_Wg, WgTE, lstm_Wih, WihT, lstm_Whh, WhhT,
                                                   convL_w, wtL, convE_w, wtE, whh_bf);
        prep_wtA<<<cdiv(CA * KPA, 256), 256, 0, stream>>>(convA_w, wtA);
        // LSTM: zx GEMV then MFMA recurrence (writes bf16 hbuf)
        zx_kernel<<<(BTOT * WE_) / 2, 256, 0, stream>>>(x_emo, lstm_Wih, zx);
        lstm_mfma<<<BTOT / 16, 512, 0, stream>>>(zx, whh_bf, lstm_bih, lstm_bhh, wlen,
                                                 (unsigned short*)hbuf);
        // convert big inputs to padded bf16 (after lstm: zx aliases xaco_p)
        cvt_both<<<4096, 256, 0, stream>>>(x_aco, x_lin, xaco_p, xlin_p);
        // pipelined MFMA convs + fused maxpool
        conv_pool_mfma<6, LOUTA, WA_, EAP, CA, KPA>
            <<<BTOT / 6, 512, 0, stream>>>(xaco_p, wtA, convA_b, pA);
        conv_pool_mfma<8, LOUTL, WL_, ELP, CL, KPL>
            <<<BTOT / 8, 512, 0, stream>>>(xlin_p, wtL, convL_b, pL);
        conv_pool_mfma<8, LOUTE, WE_, HH, CE, KPE>
            <<<BTOT / 8, 512, 0, stream>>>((const unsigned short*)hbuf, wtE, convE_b, pE);
    } else {
        prep_small<false><<<2088, 256, 0, stream>>>(hwL_Wp, WpTL, hwL_Wg, WgTL, hwA_Wp, WpTA, hwA_Wg, WgTA,
                                                    hwE_Wp, WpTE, hwE_Wg, WgTE, lstm_Wih, WihT, lstm_Whh, WhhT,
                                                    convL_w, wtL, convE_w, wtE, whh_bf);
        lstm_kernel_f32<<<BTOT, 512, 0, stream>>>(x_emo, wlen, WihT, WhhT, lstm_bih, lstm_bhh, (float*)hbuf);
        conv_pool_simple<EA, WA_, CA, KDIMA, LOUTA>
            <<<dim3(BTOT, CA / 64), 256, 0, stream>>>(x_aco, convA_w, convA_b, pA);
        conv_pool_simple<EL, WL_, CL, KDIML, LOUTL>
            <<<dim3(BTOT, CL / 64), 256, 0, stream>>>(x_lin, convL_w, convL_b, pL);
        conv_pool_simple<HH, WE_, CE, KDIME, LOUTE>
            <<<dim3(BTOT, CE / 64), 256, 0, stream>>>((const float*)hbuf, convE_w, convE_b, pE);
    }

    // ---- highways -> output concat (L:0..127, A:128..383, E:384..447) ----
    highway_kernel<CL, 0>  <<<BTOT, CL, 0, stream>>>(pL, WpTL, hwL_bp, WgTL, hwL_bg, out);
    highway_kernel<CA, 128><<<BTOT, CA, 0, stream>>>(pA, WpTA, hwA_bp, WgTA, hwA_bg, out);
    highway_kernel<CE, 384><<<BTOT, CE, 0, stream>>>(pE, WpTE, hwE_bp, WgTE, hwE_bg, out);
}

// Round 5
// 613.295 us; speedup vs baseline: 12.5340x; 1.1816x over previous
//
#include <hip/hip_runtime.h>
#include <hip/hip_bf16.h>
#include <math.h>

// ---------------- problem dims (fixed by setup_inputs) ----------------
#define BTOT 1536            // B*T = 32*48
// linguistic
#define EL 300
#define ELP 304
#define WL_ 33
#define CL 128
#define LOUTL 29
#define KPL 1536             // 48*32 (>= 5*304=1520; tail hits zero weights)
// acoustic
#define EA 988
#define EAP 992
#define WA_ 50
#define CA 256
#define LOUTA 41
#define KPA 9920             // 310*32 = 10*992 exact
// emotient
#define EE 20
#define WE_ 30
#define HH 128
#define CE 64
#define LOUTE 28
#define KPE 384              // 12*32 = 3*128 exact
// fallback K dims
#define KDIML 1500
#define KDIMA 9880
#define KDIME 384

typedef __attribute__((ext_vector_type(4))) float f32x4;
typedef __attribute__((ext_vector_type(8))) short short8;

// RNE float->bf16 (inputs finite)
__device__ __forceinline__ unsigned short f2bf(float f) {
    unsigned int x = __float_as_uint(f);
    unsigned int r = (x + 0x7fffu + ((x >> 16) & 1u)) >> 16;
    return (unsigned short)r;
}

__device__ __forceinline__ float sigmf(float x) {
    return __builtin_amdgcn_rcpf(1.f + __expf(-x));
}
__device__ __forceinline__ float tanh_fast(float x) {
    return 1.f - 2.f * __builtin_amdgcn_rcpf(1.f + __expf(2.f * x));
}

#define GLD16(gp, lp) __builtin_amdgcn_global_load_lds( \
    (const __attribute__((address_space(1))) void*)(gp), \
    (__attribute__((address_space(3))) void*)(lp), 16, 0, 0)

template<int N> __device__ __forceinline__ void vmwait() {
    if constexpr (N == 0) asm volatile("s_waitcnt vmcnt(0)" ::: "memory");
    else if constexpr (N == 2) asm volatile("s_waitcnt vmcnt(2)" ::: "memory");
    else if constexpr (N == 3) asm volatile("s_waitcnt vmcnt(3)" ::: "memory");
    else static_assert(N == 0 || N == 2 || N == 3, "add case");
}

// ================= fused small-prep kernel =================
__device__ __forceinline__ void tr_one(const float* a, float* at, int R, int C, int idx) {
    int r = idx / C, c = idx - r * C;
    at[c * R + r] = a[idx];
}
template<int CIN, int CINP, int KW, int COUT, int KPAD>
__device__ __forceinline__ void wt_one(const float* w, unsigned short* wt, int idx) {
    int co = idx / KPAD;
    int p  = idx - co * KPAD;
    int k  = p / CINP;
    int c  = p - k * CINP;
    float v = 0.f;
    if (k < KW && c < CIN) v = w[(co * CIN + c) * KW + k];
    wt[idx] = f2bf(v);
}
template<bool BIG>
__global__ void prep_small(const float* hwL_Wp, float* WpTL, const float* hwL_Wg, float* WgTL,
                           const float* hwA_Wp, float* WpTA, const float* hwA_Wg, float* WgTA,
                           const float* hwE_Wp, float* WpTE, const float* hwE_Wg, float* WgTE,
                           const float* lstm_Wih, float* WihT, const float* lstm_Whh, float* WhhT,
                           const float* convL_w, unsigned short* wtL,
                           const float* convE_w, unsigned short* wtE,
                           unsigned short* whh_bf, unsigned short* wihp_bf) {
    constexpr int S1 = 16384, S2 = 16384, S3 = 65536, S4 = 65536, S5 = 4096, S6 = 4096;
    constexpr int S7 = 512 * 20, S8 = 512 * 128;
    constexpr int S9 = 128 * KPL, S10 = 64 * KPE, S11 = 512 * 128, S12 = 512 * 32;
    constexpr int SMALL = S1 + S2 + S3 + S4 + S5 + S6 + S7 + S8;
    constexpr int TOTAL = BIG ? (SMALL + S9 + S10 + S11 + S12) : SMALL;
    int stride = gridDim.x * blockDim.x;
    for (int i = blockIdx.x * blockDim.x + threadIdx.x; i < TOTAL; i += stride) {
        int idx = i;
        if (idx < S1) { tr_one(hwL_Wp, WpTL, 128, 128, idx); continue; } idx -= S1;
        if (idx < S2) { tr_one(hwL_Wg, WgTL, 128, 128, idx); continue; } idx -= S2;
        if (idx < S3) { tr_one(hwA_Wp, WpTA, 256, 256, idx); continue; } idx -= S3;
        if (idx < S4) { tr_one(hwA_Wg, WgTA, 256, 256, idx); continue; } idx -= S4;
        if (idx < S5) { tr_one(hwE_Wp, WpTE, 64, 64, idx); continue; } idx -= S5;
        if (idx < S6) { tr_one(hwE_Wg, WgTE, 64, 64, idx); continue; } idx -= S6;
        if (idx < S7) { tr_one(lstm_Wih, WihT, 512, 20, idx); continue; } idx -= S7;
        if (idx < S8) { tr_one(lstm_Whh, WhhT, 512, 128, idx); continue; } idx -= S8;
        if constexpr (BIG) {
            if (idx < S9) { wt_one<EL, ELP, 5, CL, KPL>(convL_w, wtL, idx); continue; } idx -= S9;
            if (idx < S10) { wt_one<HH, HH, 3, CE, KPE>(convE_w, wtE, idx); continue; } idx -= S10;
            if (idx < S11) { whh_bf[idx] = f2bf(lstm_Whh[idx]); continue; } idx -= S11;
            { int col = idx >> 5, e = idx & 31;
              wihp_bf[idx] = (e < 20) ? f2bf(lstm_Wih[col * 20 + e]) : (unsigned short)0; }
        }
    }
}

__global__ void prep_wtA(const float* __restrict__ w, unsigned short* __restrict__ wt) {
    int idx = blockIdx.x * blockDim.x + threadIdx.x;
    if (idx >= CA * KPA) return;
    wt_one<EA, EAP, 10, CA, KPA>(w, wt, idx);
}

// ---------------- fused fp32->bf16 pad convert for both big inputs ----------------
template<int CIN, int CINP>
__device__ __forceinline__ void cvt_chunk(const float* in, unsigned short* out, int idx) {
    constexpr int CH = CINP / 8;
    int row = idx / CH, c0 = (idx - row * CH) * 8;
    const float* src = in + (size_t)row * CIN + c0;
    union { short8 s; unsigned short u[8]; } o;
    if (c0 + 8 <= CIN) {
        float4 v0 = *(const float4*)src;
        float4 v1 = *(const float4*)(src + 4);
        o.u[0]=f2bf(v0.x); o.u[1]=f2bf(v0.y); o.u[2]=f2bf(v0.z); o.u[3]=f2bf(v0.w);
        o.u[4]=f2bf(v1.x); o.u[5]=f2bf(v1.y); o.u[6]=f2bf(v1.z); o.u[7]=f2bf(v1.w);
    } else {
        #pragma unroll
        for (int j = 0; j < 8; ++j) o.u[j] = (c0 + j < CIN) ? f2bf(src[j]) : (unsigned short)0;
    }
    *(short8*)(out + (size_t)row * CINP + c0) = o.s;
}
__global__ void cvt_both(const float* __restrict__ xa, const float* __restrict__ xl,
                         unsigned short* __restrict__ outa, unsigned short* __restrict__ outl) {
    constexpr int NAC = (BTOT * WA_) * (EAP / 8);
    constexpr int NLC = (BTOT * WL_) * (ELP / 8);
    int stride = gridDim.x * blockDim.x;
    for (int i = blockIdx.x * blockDim.x + threadIdx.x; i < NAC + NLC; i += stride) {
        if (i < NAC) cvt_chunk<EA, EAP>(xa, outa, i);
        else         cvt_chunk<EL, ELP>(xl, outl, i - NAC);
    }
}

// ================= conv1d GEMM (bf16 MFMA), BM=128/BK=32, 3-stage ring, 1 barrier/step =================
// xb: bf16 (BTOT, WIN, CINP); A-row (bt,l) = xb[bt, l*CINP ..]. wt: bf16 [COUT][KPAD].
// pooled[bt][co] = max_l conv + bias[co].
template<int NBT, int LOUT, int WIN, int CINP, int COUT, int KPAD>
__global__ __launch_bounds__(512, 4)
void conv_pool_v5(const unsigned short* __restrict__ xb, const unsigned short* __restrict__ wt,
                  const float* __restrict__ bias, float* __restrict__ pooled)
{
    constexpr int NF   = COUT / 64;          // per-wave 16-col frags (4/2/1)
    constexpr int NK   = KPAD / 32;
    constexpr int NBU  = COUT / 16;          // B wave-units (1 KB each)
    constexpr int BWI  = (NBU > 8) ? NBU / 8 : 1;
    constexpr int VMN  = 1 + BWI;            // per-wave gld per stage
    constexpr int ABY  = 128 * 64;           // 8 KB
    constexpr int BUFB = ABY + COUT * 64;
    constexpr int MVAL = NBT * LOUT;

    __shared__ __align__(16) char smem[3 * BUFB > 32768 ? 3 * BUFB : 32768];

    const int tid  = threadIdx.x;
    const int lane = tid & 63;
    const int wid  = tid >> 6;
    const int wm   = wid >> 2;        // 0..1 : row half
    const int wn   = wid & 3;         // 0..3 : col quarter
    const int lr   = lane & 15;
    const int lq   = lane >> 4;
    const int bx   = blockIdx.x;

    f32x4 acc[4][NF];
    #pragma unroll
    for (int i = 0; i < 4; ++i)
        #pragma unroll
        for (int j = 0; j < NF; ++j) acc[i][j] = (f32x4){0.f, 0.f, 0.f, 0.f};

    // A source row base for this wave's staging lane (constant over K)
    const int sr   = wid * 16 + (lane >> 2);        // staged A row 0..127
    const int sslt = lane & 3;                      // 16B slot in 64B
    int rv = (sr < MVAL) ? sr : (MVAL - 1);
    int sbtl = rv / LOUT;
    int sl   = rv - sbtl * LOUT;
    const char* asrc0 = (const char*)xb + (((size_t)(bx * NBT + sbtl) * WIN + sl) * CINP) * 2
                      + ((sslt * 16) ^ (((sr >> 2) & 3) << 4));

    auto STAGE = [&](int ts, int buf) {
        char* db = smem + buf * BUFB;
        GLD16(asrc0 + (size_t)ts * 64, db + wid * 1024 + lane * 16);
        #pragma unroll
        for (int i = 0; i < BWI; ++i) {
            int bu = (NBU > 8) ? (wid + i * 8) : (wid & (NBU - 1));
            int col = bu * 16 + (lane >> 2);
            const char* src = (const char*)wt + (size_t)col * KPAD * 2
                + (size_t)ts * 64 + ((sslt * 16) ^ (((col >> 2) & 3) << 4));
            GLD16(src, db + ABY + bu * 1024 + lane * 16);
        }
    };

    STAGE(0, 0);
    STAGE(1, 1);
    vmwait<VMN>();
    __builtin_amdgcn_s_barrier();

    const int ra = wm * 64 + lr;
    int cur = 0;
    for (int t = 0; t < NK; ++t) {
        const char* sA = smem + cur * BUFB;
        const char* sB = sA + ABY;
        short8 a[4];
        #pragma unroll
        for (int o = 0; o < 4; ++o) {
            int r = ra + o * 16;
            a[o] = *(const short8*)(sA + (size_t)r * 64 + ((lq * 16) ^ (((r >> 2) & 3) << 4)));
        }
        short8 bfr[NF];
        #pragma unroll
        for (int nf = 0; nf < NF; ++nf) {
            int cb = wn * (16 * NF) + nf * 16 + lr;
            bfr[nf] = *(const short8*)(sB + (size_t)cb * 64 + ((lq * 16) ^ (((cb >> 2) & 3) << 4)));
        }
        int wb = cur + 2; if (wb >= 3) wb -= 3;
        if (t + 2 < NK) STAGE(t + 2, wb);
        asm volatile("s_waitcnt lgkmcnt(0)" ::: "memory");
        __builtin_amdgcn_sched_barrier(0);
        __builtin_amdgcn_s_setprio(1);
        #pragma unroll
        for (int nf = 0; nf < NF; ++nf)
            #pragma unroll
            for (int o = 0; o < 4; ++o)
                acc[o][nf] = __builtin_amdgcn_mfma_f32_16x16x32_bf16(a[o], bfr[nf], acc[o][nf], 0, 0, 0);
        __builtin_amdgcn_s_setprio(0);
        if (t + 2 < NK) vmwait<VMN>(); else vmwait<0>();
        asm volatile("" ::: "memory");
        __builtin_amdgcn_s_barrier();
        cur = cur + 1; if (cur >= 3) cur -= 3;
    }
    __syncthreads();

    // ---- fused maxpool epilogue: reuse smem as swizzled [128][64] f32 ----
    for (int nf = 0; nf < NF; ++nf) {
        #pragma unroll
        for (int m = 0; m < 4; ++m) {
            int row = wm * 64 + m * 16 + lq * 4;
            int cs  = wn * 16 + lr;
            f32x4 v = acc[m][nf];
            #pragma unroll
            for (int r = 0; r < 4; ++r)
                *(float*)(smem + (size_t)(row + r) * 256 + ((cs * 4) ^ (((row + r) & 7) << 4))) = v[r];
        }
        __syncthreads();
        if (tid < 64 * NBT) {
            int btl = tid >> 6, cs = tid & 63;
            int base = btl * LOUT;
            float m = *(const float*)(smem + (size_t)base * 256 + ((cs * 4) ^ ((base & 7) << 4)));
            for (int l = 1; l < LOUT; ++l) {
                int rr = base + l;
                m = fmaxf(m, *(const float*)(smem + (size_t)rr * 256 + ((cs * 4) ^ ((rr & 7) << 4))));
            }
            int col = (cs >> 4) * (16 * NF) + nf * 16 + (cs & 15);
            int bt  = bx * NBT + btl;
            pooled[(size_t)bt * COUT + col] = m + bias[col];
        }
        __syncthreads();
    }
}

// ================= masked LSTM via MFMA, fully fused (x@Wih + h@Whh in-kernel) =================
// 16 samples/block, 96 blocks. wihp_bf: [512][32] (k-padded), whh_bf: [512][128].
__global__ __launch_bounds__(512, 1)
void lstm_mfma(const float* __restrict__ x_emo,
               const unsigned short* __restrict__ wihp_bf, const unsigned short* __restrict__ whh_bf,
               const float* __restrict__ bih, const float* __restrict__ bhh,
               const int* __restrict__ lens, unsigned short* __restrict__ hbuf)
{
    __shared__ __align__(16) unsigned short xq[WE_ * 16 * 32];  // [t][s][e pad 32] 30 KB
    __shared__ __align__(16) char h_s[2 * 16 * HH * 2];         // 8 KB dbuf, swizzled

    const int tid  = threadIdx.x;
    const int w    = tid >> 6;
    const int lane = tid & 63;
    const int lr   = lane & 15;
    const int lq   = lane >> 4;
    const int s0   = blockIdx.x * 16;
    const int c    = w * 16 + lr;     // gate-col within 128

    short8 bfr[4][4];  // Whh frags per gate
    short8 bw[4];      // Wih frags per gate
    float bj[4];
    #pragma unroll
    for (int g = 0; g < 4; ++g) {
        int col = g * 128 + c;
        #pragma unroll
        for (int kt = 0; kt < 4; ++kt)
            bfr[g][kt] = *(const short8*)(whh_bf + (size_t)col * 128 + kt * 32 + lq * 8);
        bw[g] = *(const short8*)(wihp_bf + (size_t)col * 32 + lq * 8);
        bj[g] = bih[col] + bhh[col];
    }
    int len4[4];
    #pragma unroll
    for (int j = 0; j < 4; ++j) len4[j] = lens[s0 + lq * 4 + j];

    // load x tile: [t][s][e], e padded 20->32 with zeros
    for (int i = tid; i < WE_ * 16 * 32; i += 512) {
        int t = i >> 9, r = (i >> 5) & 15, e = i & 31;
        xq[i] = (e < 20) ? f2bf(x_emo[(((size_t)(s0 + r) * WE_) + t) * 20 + e]) : (unsigned short)0;
    }
    for (int i = tid; i < 2048; i += 512) ((unsigned int*)h_s)[i] = 0u;

    float c_prev[4] = {0.f, 0.f, 0.f, 0.f};
    unsigned short hb_prev[4] = {0, 0, 0, 0};
    __syncthreads();

    for (int t = 0; t < WE_; ++t) {
        const char* hsr = h_s + (t & 1) * 4096;
        char* hsw = h_s + ((t & 1) ^ 1) * 4096;
        short8 ax = *(const short8*)((const char*)xq + (size_t)(t * 16 + lr) * 64 + lq * 16);
        short8 af[4];
        #pragma unroll
        for (int kt = 0; kt < 4; ++kt)
            af[kt] = *(const short8*)(hsr + ((lr * 256 + kt * 64 + lq * 16) ^ ((lr & 7) << 4)));
        f32x4 acc[4];
        #pragma unroll
        for (int g = 0; g < 4; ++g)
            acc[g] = __builtin_amdgcn_mfma_f32_16x16x32_bf16(ax, bw[g], (f32x4){0.f,0.f,0.f,0.f}, 0, 0, 0);
        #pragma unroll
        for (int kt = 0; kt < 4; ++kt)
            #pragma unroll
            for (int g = 0; g < 4; ++g)
                acc[g] = __builtin_amdgcn_mfma_f32_16x16x32_bf16(af[kt], bfr[g][kt], acc[g], 0, 0, 0);
        #pragma unroll
        for (int j = 0; j < 4; ++j) {
            int s = lq * 4 + j;
            float zi = acc[0][j] + bj[0];
            float zf = acc[1][j] + bj[1];
            float zg = acc[2][j] + bj[2];
            float zo = acc[3][j] + bj[3];
            float si = sigmf(zi), sf = sigmf(zf), so = sigmf(zo);
            float tg = tanh_fast(zg);
            float c2 = sf * c_prev[j] + si * tg;
            float h2 = so * tanh_fast(c2);
            bool valid = (t < len4[j]);
            c_prev[j] = valid ? c2 : c_prev[j];
            unsigned short h2b = f2bf(h2);
            unsigned short hn = valid ? h2b : hb_prev[j];
            hb_prev[j] = hn;
            *(unsigned short*)(hsw + (((s * HH + c) * 2) ^ ((s & 7) << 4))) = hn;
            hbuf[(((size_t)(s0 + s) * WE_) + t) * HH + c] = valid ? h2b : (unsigned short)0;
        }
        __syncthreads();
    }
}

// ---------------- highway ----------------
template<int C, int OFF>
__global__ void highway_kernel(const float* __restrict__ pooled,
                               const float* __restrict__ WpT, const float* __restrict__ bp,
                               const float* __restrict__ WgT, const float* __restrict__ bg,
                               float* __restrict__ out) {
    int bt = blockIdx.x;
    int j  = threadIdx.x;
    __shared__ float xs[C];
    xs[j] = pooled[(size_t)bt * C + j];
    __syncthreads();
    float ap = bp[j], ag = bg[j];
    for (int cc = 0; cc < C; ++cc) {
        float xv = xs[cc];
        ap += xv * WpT[cc * C + j];
        ag += xv * WgT[cc * C + j];
    }
    float p = fmaxf(ap, 0.f);
    float g = sigmf(ag);
    out[(size_t)bt * 448 + OFF + j] = g * p + (1.f - g) * xs[j];
}

// ================= fallback path (tiny workspace): slow but correct =================
__global__ __launch_bounds__(512)
void lstm_kernel_f32(const float* __restrict__ x, const int* __restrict__ lens,
                     const float* __restrict__ WihT, const float* __restrict__ WhhT,
                     const float* __restrict__ bih, const float* __restrict__ bhh,
                     float* __restrict__ hout) {
    int bt = blockIdx.x;
    int j  = threadIdx.x;
    __shared__ float xs[WE_][EE];
    __shared__ __align__(16) float hs[HH];
    __shared__ float zs[512];
    for (int idx = j; idx < WE_ * EE; idx += 512)
        ((float*)xs)[idx] = x[(size_t)bt * WE_ * EE + idx];
    if (j < HH) hs[j] = 0.f;
    float wih[EE];
    #pragma unroll
    for (int e = 0; e < EE; ++e) wih[e] = WihT[e * 512 + j];
    float whh[HH];
    #pragma unroll
    for (int h = 0; h < HH; ++h) whh[h] = WhhT[h * 512 + j];
    float bjv = bih[j] + bhh[j];
    float c_reg = 0.f;
    int len = lens[bt];
    __syncthreads();
    for (int t = 0; t < WE_; ++t) {
        float z = bjv;
        #pragma unroll
        for (int e = 0; e < EE; ++e) z += wih[e] * xs[t][e];
        const float4* h4 = (const float4*)hs;
        #pragma unroll
        for (int q = 0; q < HH / 4; ++q) {
            float4 hv = h4[q];
            z += whh[4*q+0] * hv.x + whh[4*q+1] * hv.y
               + whh[4*q+2] * hv.z + whh[4*q+3] * hv.w;
        }
        zs[j] = z;
        __syncthreads();
        if (j < HH) {
            float zi = zs[j], zf = zs[HH + j], zg = zs[2*HH + j], zo = zs[3*HH + j];
            float si = 1.f / (1.f + expf(-zi));
            float sf = 1.f / (1.f + expf(-zf));
            float so = 1.f / (1.f + expf(-zo));
            float tg = tanhf(zg);
            float c2 = sf * c_reg + si * tg;
            float h2 = so * tanhf(c2);
            bool valid = (t < len);
            float hn = valid ? h2 : hs[j];
            c_reg    = valid ? c2 : c_reg;
            hout[((size_t)bt * WE_ + t) * HH + j] = valid ? h2 : 0.f;
            hs[j] = hn;
        }
        __syncthreads();
    }
}

template<int CIN, int WIN, int COUT, int KDIM, int LOUT>
__global__ __launch_bounds__(256)
void conv_pool_simple(const float* __restrict__ x, const float* __restrict__ w,
                      const float* __restrict__ bias, float* __restrict__ pooled)
{
    constexpr int KW = KDIM / CIN;
    int bt = blockIdx.x;
    int co = blockIdx.y * 64 + (threadIdx.x & 63);
    int seg = threadIdx.x >> 6;
    __shared__ float part[4][64];
    float m = -INFINITY;
    for (int l = seg; l < LOUT; l += 4) {
        float acc = 0.f;
        for (int k = 0; k < KW; ++k) {
            const float* xr = x + ((size_t)bt * WIN + l + k) * CIN;
            const float* wr = w + ((size_t)co * CIN) * KW + k;
            for (int cc = 0; cc < CIN; ++cc) acc += xr[cc] * wr[(size_t)cc * KW];
        }
        m = fmaxf(m, acc);
    }
    part[seg][threadIdx.x & 63] = m;
    __syncthreads();
    if (threadIdx.x < 64) {
        float mm = fmaxf(fmaxf(part[0][threadIdx.x], part[1][threadIdx.x]),
                         fmaxf(part[2][threadIdx.x], part[3][threadIdx.x]));
        pooled[(size_t)bt * COUT + co] = mm + bias[co];
    }
}

// ---------------- launch ----------------
static inline int cdiv(int a, int b) { return (a + b - 1) / b; }

extern "C" void kernel_launch(void* const* d_in, const int* in_sizes, int n_in,
                              void* d_out, int out_size, void* d_ws, size_t ws_size,
                              hipStream_t stream) {
    const float* x_lin  = (const float*)d_in[0];
    const float* x_aco  = (const float*)d_in[1];
    const float* x_emo  = (const float*)d_in[2];
    const int*   wlen   = (const int*)  d_in[3];
    const float* convL_w = (const float*)d_in[5];
    const float* convL_b = (const float*)d_in[6];
    const float* convA_w = (const float*)d_in[7];
    const float* convA_b = (const float*)d_in[8];
    const float* convE_w = (const float*)d_in[9];
    const float* convE_b = (const float*)d_in[10];
    const float* hwL_Wp = (const float*)d_in[11];
    const float* hwL_bp = (const float*)d_in[12];
    const float* hwL_Wg = (const float*)d_in[13];
    const float* hwL_bg = (const float*)d_in[14];
    const float* hwA_Wp = (const float*)d_in[15];
    const float* hwA_bp = (const float*)d_in[16];
    const float* hwA_Wg = (const float*)d_in[17];
    const float* hwA_bg = (const float*)d_in[18];
    const float* hwE_Wp = (const float*)d_in[19];
    const float* hwE_bp = (const float*)d_in[20];
    const float* hwE_Wg = (const float*)d_in[21];
    const float* hwE_bg = (const float*)d_in[22];
    const float* lstm_Wih = (const float*)d_in[23];
    const float* lstm_Whh = (const float*)d_in[24];
    const float* lstm_bih = (const float*)d_in[25];
    const float* lstm_bhh = (const float*)d_in[26];
    float* out = (float*)d_out;

    // ---- workspace carve (256B aligned) ----
    char* p0 = (char*)d_ws;
    char* p = p0;
    auto alloc = [&](size_t bytes) { char* r = p; p += (bytes + 255) & ~(size_t)255; return r; };
    float* WpTL = (float*)alloc((size_t)CL * CL * 4);
    float* WgTL = (float*)alloc((size_t)CL * CL * 4);
    float* WpTA = (float*)alloc((size_t)CA * CA * 4);
    float* WgTA = (float*)alloc((size_t)CA * CA * 4);
    float* WpTE = (float*)alloc((size_t)CE * CE * 4);
    float* WgTE = (float*)alloc((size_t)CE * CE * 4);
    float* WihT = (float*)alloc((size_t)EE * 512 * 4);
    float* WhhT = (float*)alloc((size_t)HH * 512 * 4);
    unsigned short* whh_bf  = (unsigned short*)alloc((size_t)512 * 128 * 2);
    unsigned short* wihp_bf = (unsigned short*)alloc((size_t)512 * 32 * 2);
    void*  hbuf = (void*)alloc((size_t)BTOT * WE_ * HH * 4);    // f32-sized; fast path uses bf16 half
    float* pL   = (float*)alloc((size_t)BTOT * CL * 4);
    float* pA   = (float*)alloc((size_t)BTOT * CA * 4);
    float* pE   = (float*)alloc((size_t)BTOT * CE * 4);
    unsigned short* wtA = (unsigned short*)alloc((size_t)CA * KPA * 2);
    unsigned short* wtL = (unsigned short*)alloc((size_t)CL * KPL * 2);
    unsigned short* wtE = (unsigned short*)alloc((size_t)CE * KPE * 2);
    unsigned short* xlin_p = (unsigned short*)alloc((size_t)BTOT * WL_ * ELP * 2 + 64);
    unsigned short* xaco_p = (unsigned short*)alloc((size_t)BTOT * WA_ * EAP * 2 + 64);
    size_t need = (size_t)(p - p0);
    bool big = ws_size >= need;

    if (big) {
        prep_small<true><<<2048, 256, 0, stream>>>(hwL_Wp, WpTL, hwL_Wg, WgTL, hwA_Wp, WpTA, hwA_Wg, WgTA,
                                                   hwE_Wp, WpTE, hwE_Wg, WgTE, lstm_Wih, WihT, lstm_Whh, WhhT,
                                                   convL_w, wtL, convE_w, wtE, whh_bf, wihp_bf);
        prep_wtA<<<cdiv(CA * KPA, 256), 256, 0, stream>>>(convA_w, wtA);
        lstm_mfma<<<BTOT / 16, 512, 0, stream>>>(x_emo, wihp_bf, whh_bf, lstm_bih, lstm_bhh, wlen,
                                                 (unsigned short*)hbuf);
        cvt_both<<<4096, 256, 0, stream>>>(x_aco, x_lin, xaco_p, xlin_p);
        conv_pool_v5<3, LOUTA, WA_, EAP, CA, KPA>
            <<<BTOT / 3, 512, 0, stream>>>(xaco_p, wtA, convA_b, pA);
        conv_pool_v5<4, LOUTL, WL_, ELP, CL, KPL>
            <<<BTOT / 4, 512, 0, stream>>>(xlin_p, wtL, convL_b, pL);
        conv_pool_v5<4, LOUTE, WE_, HH, CE, KPE>
            <<<BTOT / 4, 512, 0, stream>>>((const unsigned short*)hbuf, wtE, convE_b, pE);
    } else {
        prep_small<false><<<2048, 256, 0, stream>>>(hwL_Wp, WpTL, hwL_Wg, WgTL, hwA_Wp, WpTA, hwA_Wg, WgTA,
                                                    hwE_Wp, WpTE, hwE_Wg, WgTE, lstm_Wih, WihT, lstm_Whh, WhhT,
                                                    convL_w, wtL, convE_w, wtE, whh_bf, wihp_bf);
        lstm_kernel_f32<<<BTOT, 512, 0, stream>>>(x_emo, wlen, WihT, WhhT, lstm_bih, lstm_bhh, (float*)hbuf);
        conv_pool_simple<EA, WA_, CA, KDIMA, LOUTA>
            <<<dim3(BTOT, CA / 64), 256, 0, stream>>>(x_aco, convA_w, convA_b, pA);
        conv_pool_simple<EL, WL_, CL, KDIML, LOUTL>
            <<<dim3(BTOT, CL / 64), 256, 0, stream>>>(x_lin, convL_w, convL_b, pL);
        conv_pool_simple<HH, WE_, CE, KDIME, LOUTE>
            <<<dim3(BTOT, CE / 64), 256, 0, stream>>>((const float*)hbuf, convE_w, convE_b, pE);
    }

    // ---- highways -> output concat (L:0..127, A:128..383, E:384..447) ----
    highway_kernel<CL, 0>  <<<BTOT, CL, 0, stream>>>(pL, WpTL, hwL_bp, WgTL, hwL_bg, out);
    highway_kernel<CA, 128><<<BTOT, CA, 0, stream>>>(pA, WpTA, hwA_bp, WgTA, hwA_bg, out);
    highway_kernel<CE, 384><<<BTOT, CE, 0, stream>>>(pE, WpTE, hwE_bp, WgTE, hwE_bg, out);
}